// Round 16
// baseline (2932.221 us; speedup 1.0000x reference)
//
#include <hip/hip_runtime.h>

#define S_ 160
#define B_ 64
#define H_ 1024
#define E_ 512
#define V_ 64
#define T_ 16
#define H4_ 4096

__device__ __forceinline__ float sigm(float x) { return 1.f / (1.f + expf(-x)); }

// ---------------------------------------------------------------------------
// C = A @ Bm^T + bias. 128x128 tile, BK=16, 512 threads, 4x8 acc/thread.
// (validated round 15)
// ---------------------------------------------------------------------------
__global__ __launch_bounds__(512) void gemm_bt_128(
    const float* __restrict__ A, const float* __restrict__ Bm,
    const float* __restrict__ bias, float* __restrict__ Cd,
    int M, int N, int K)
{
    __shared__ float As[16][132];
    __shared__ float Bs[16][132];
    const int bn = blockIdx.x, bm = blockIdx.y;
    const int tid = threadIdx.x;
    const int lr = tid >> 2, lk = (tid & 3) * 4;
    const int cx4 = (tid & 15) * 4, ry4 = (tid >> 4) * 4;
    const float* Ap = A + (size_t)(bm * 128 + lr) * K + lk;
    const float* Bp = Bm + (size_t)(bn * 128 + lr) * K + lk;
    float acc[4][8] = {};
    for (int k0 = 0; k0 < K; k0 += 16) {
        float4 av = *(const float4*)(Ap + k0);
        float4 bv = *(const float4*)(Bp + k0);
        __syncthreads();
        As[lk + 0][lr] = av.x; As[lk + 1][lr] = av.y;
        As[lk + 2][lr] = av.z; As[lk + 3][lr] = av.w;
        Bs[lk + 0][lr] = bv.x; Bs[lk + 1][lr] = bv.y;
        Bs[lk + 2][lr] = bv.z; Bs[lk + 3][lr] = bv.w;
        __syncthreads();
#pragma unroll
        for (int kk = 0; kk < 16; ++kk) {
            float a[4], b[8];
            *(float4*)(a)     = *(const float4*)&As[kk][ry4];
            *(float4*)(b)     = *(const float4*)&Bs[kk][cx4];
            *(float4*)(b + 4) = *(const float4*)&Bs[kk][64 + cx4];
#pragma unroll
            for (int i = 0; i < 4; ++i)
#pragma unroll
                for (int j = 0; j < 8; ++j) acc[i][j] = fmaf(a[i], b[j], acc[i][j]);
        }
    }
#pragma unroll
    for (int i = 0; i < 4; ++i) {
        int row = bm * 128 + ry4 + i;
#pragma unroll
        for (int j = 0; j < 8; ++j) {
            int col = bn * 128 + ((j < 4) ? (cx4 + j) : (64 + cx4 + j - 4));
            Cd[(size_t)row * N + col] = acc[i][j] + bias[col];
        }
    }
}

// 64x64 tile GEMM helper (BK=16). Strides baked into Arow/Brow pointers.
__device__ __forceinline__ void tile64(const float* __restrict__ Arow,
                                       const float* __restrict__ Brow,
                                       int K, float acc[4][4],
                                       float* __restrict__ As,
                                       float* __restrict__ Bs)
{
    const int tid = threadIdx.x;
    const int lr = tid >> 2, lc = (tid & 3) << 2;
    const int tx = tid & 15, ty = tid >> 4;
    for (int k0 = 0; k0 < K; k0 += 16) {
        float4 av = *(const float4*)(Arow + k0);
        float4 bv = *(const float4*)(Brow + k0);
        __syncthreads();
        As[lr * 17 + lc + 0] = av.x; As[lr * 17 + lc + 1] = av.y;
        As[lr * 17 + lc + 2] = av.z; As[lr * 17 + lc + 3] = av.w;
        Bs[lr * 17 + lc + 0] = bv.x; Bs[lr * 17 + lc + 1] = bv.y;
        Bs[lr * 17 + lc + 2] = bv.z; Bs[lr * 17 + lc + 3] = bv.w;
        __syncthreads();
#pragma unroll
        for (int kk = 0; kk < 16; ++kk) {
            float a[4], b[4];
#pragma unroll
            for (int i = 0; i < 4; ++i) a[i] = As[(ty * 4 + i) * 17 + kk];
#pragma unroll
            for (int j = 0; j < 4; ++j) b[j] = Bs[(tx * 4 + j) * 17 + kk];
#pragma unroll
            for (int i = 0; i < 4; ++i)
#pragma unroll
                for (int j = 0; j < 4; ++j) acc[i][j] = fmaf(a[i], b[j], acc[i][j]);
        }
    }
    __syncthreads();
}

// Split-K partials: Cpart[kz][M][N]. KS==1 -> plain GEMM to Cpart.
__global__ __launch_bounds__(256) void gemm_part(
    const float* __restrict__ A, const float* __restrict__ Bm,
    float* __restrict__ Cpart, int M, int N, int K)
{
    __shared__ float smem[2176];
    const int bn = blockIdx.x, bm = blockIdx.y, kz = blockIdx.z, KS = gridDim.z;
    const int tid = threadIdx.x;
    const int lr = tid >> 2, lc = (tid & 3) << 2;
    const int tx = tid & 15, ty = tid >> 4;
    const int kLen = K / KS, k0base = kz * kLen;
    float acc[4][4] = {};
    tile64(A + (size_t)(bm * 64 + lr) * K + k0base + lc,
           Bm + (size_t)(bn * 64 + lr) * K + k0base + lc,
           kLen, acc, smem, smem + 1088);
    float* Cp = Cpart + (size_t)kz * M * N;
#pragma unroll
    for (int i = 0; i < 4; ++i) {
        int row = bm * 64 + ty * 4 + i;
#pragma unroll
        for (int j = 0; j < 4; ++j)
            Cp[(size_t)row * N + bn * 64 + tx * 4 + j] = acc[i][j];
    }
}

__global__ void reduce_partials(const float* __restrict__ Cpart, int KS,
                                const float* __restrict__ bias,
                                const float* __restrict__ bias2,
                                float* __restrict__ C, int MN, int N)
{
    int idx = blockIdx.x * 256 + threadIdx.x;
    if (idx >= MN) return;
    float v = 0.f;
    for (int z = 0; z < KS; ++z) v += Cpart[(size_t)z * MN + idx];
    int col = idx % N;
    if (bias)  v += bias[col];
    if (bias2) v += bias2[col];
    C[idx] = v;
}

// emb_ext rows 0..63 = embed, 64 = tok_emb(SOS), 65..127 = 0; zero accums.
__global__ void init_k(const float* __restrict__ embed, const float* __restrict__ tok_emb,
                       float* __restrict__ emb_ext,
                       float* __restrict__ negent, float* __restrict__ logp)
{
    int i = blockIdx.x * 256 + threadIdx.x;
    if (i < 128 * E_) {
        int r = i >> 9, c = i & (E_ - 1);
        emb_ext[i] = (r < 64) ? embed[r * E_ + c] : ((r == 64) ? tok_emb[c] : 0.f);
    }
    if (i < B_) { negent[i] = 0.f; logp[i] = 0.f; }
}

// ---------------------------------------------------------------------------
// out_h_all[(v*64+b)][h] = LSTM(all_gates[v] + hh_gates[b]) for v<66, b<64.
// Pure elementwise, 1 cell/thread, 16896 blocks.
// ---------------------------------------------------------------------------
__global__ __launch_bounds__(256) void outh_all_k(
    const float* __restrict__ all_gates, const float* __restrict__ hh_gates,
    const float* __restrict__ enc_c0, float* __restrict__ outh)
{
    size_t idx = (size_t)blockIdx.x * 256 + threadIdx.x;   // 66*64*1024
    int row = (int)(idx >> 10), h = (int)(idx & (H_ - 1));
    int v = row >> 6, b = row & 63;
    const float* ag = all_gates + (size_t)v * H4_;
    const float* hg = hh_gates + (size_t)b * H4_;
    float gi = ag[h]          + hg[h];
    float gf = ag[H_ + h]     + hg[H_ + h];
    float gg = ag[2 * H_ + h] + hg[2 * H_ + h];
    float go = ag[3 * H_ + h] + hg[3 * H_ + h];
    float cc = sigm(gf) * enc_c0[(size_t)b * H_ + h] + sigm(gi) * tanhf(gg);
    outh[idx] = sigm(go) * tanhf(cc);
}

// lg_h_all[row][v] = out_h_all[row] . out_W[v][H:2H] + out_b[v].  66 blocks.
__global__ __launch_bounds__(256) void lgh_k(
    const float* __restrict__ outh, const float* __restrict__ out_W,
    const float* __restrict__ out_b, float* __restrict__ lgh)
{
    __shared__ float smem[2176];
    const int bm = blockIdx.x;
    const int tid = threadIdx.x;
    const int lr = tid >> 2, lc = (tid & 3) << 2;
    const int tx = tid & 15, ty = tid >> 4;
    float acc[4][4] = {};
    tile64(outh + (size_t)(bm * 64 + lr) * H_ + lc,
           out_W + (size_t)lr * (2 * H_) + H_ + lc,
           H_, acc, smem, smem + 1088);
#pragma unroll
    for (int i = 0; i < 4; ++i) {
        int row = bm * 64 + ty * 4 + i;
#pragma unroll
        for (int j = 0; j < 4; ++j) {
            int col = tx * 4 + j;
            lgh[(size_t)row * V_ + col] = acc[i][j] + out_b[col];
        }
    }
}

// ---------------------------------------------------------------------------
// ONE kernel per decode step. 64 blocks (one per b) x 512 threads (8 waves).
// scores (8w x 20s from dec_sel) -> softmax+attn-out -> context -> ctx-half
// logits + lg_sel -> renorm softmax/argmax/stats -> value-gather next
// dec_sel/lg_sel (tok never leaves the kernel).
// ---------------------------------------------------------------------------
__global__ __launch_bounds__(512) void step_k(
    const float* __restrict__ enc_t, const float* __restrict__ enc_out,
    const float* __restrict__ dsrc, const float* __restrict__ lsrc,
    const float* __restrict__ attn_W, const float* __restrict__ attn_b,
    const int* __restrict__ lens, const float* __restrict__ out_W,
    const float* __restrict__ dec_all, const float* __restrict__ lg_h_all,
    float* __restrict__ dec_sel, float* __restrict__ lg_sel,
    float* __restrict__ negent_acc, float* __restrict__ logp_acc,
    float* __restrict__ out, int t)
{
    __shared__ float sc[S_];
    __shared__ float comb[H_];
    __shared__ float lg[V_];
    __shared__ int tok_s;
    const int tid = threadIdx.x;
    const int b = blockIdx.x;
    const int lane = tid & 63, wv = tid >> 6;
    const int len = lens[b];
    {   // ---- scores: wave wv handles s in [wv*20, wv*20+20) ----
        float dec_r[16], aw_r[16];
        const float* dr = dsrc + (size_t)b * H_;
#pragma unroll
        for (int it = 0; it < 16; ++it) {
            int h = lane + it * 64;
            dec_r[it] = dr[h];           // includes dec_b (GEMM bias)
            aw_r[it] = attn_W[h];
        }
        const float ab = attn_b[0];
        for (int i = 0; i < 20; ++i) {
            int s = wv * 20 + i;
            if (s >= len) { if (lane == 0) sc[s] = -1e9f; continue; }
            const float* ep = enc_t + ((size_t)s * B_ + b) * H_;
            float acc = 0.f;
#pragma unroll
            for (int it = 0; it < 16; ++it)
                acc += aw_r[it] * tanhf(ep[lane + it * 64] + dec_r[it]);
            for (int d = 32; d; d >>= 1) acc += __shfl_xor(acc, d);
            if (lane == 0) sc[s] = acc + ab;
        }
    }
    __syncthreads();
    if (wv == 0) {   // ---- masked softmax + attn-map out ----
        float m = -1e30f;
        for (int s = lane; s < S_; s += 64) m = fmaxf(m, sc[s]);
        for (int d = 32; d; d >>= 1) m = fmaxf(m, __shfl_xor(m, d));
        float sum = 0.f;
        for (int s = lane; s < S_; s += 64) {
            float e = expf(sc[s] - m); sc[s] = e; sum += e;
        }
        for (int d = 32; d; d >>= 1) sum += __shfl_xor(sum, d);
        float inv = 1.f / sum;
        for (int s = lane; s < S_; s += 64) {
            float pr = sc[s] * inv; sc[s] = pr;
            out[T_ * B_ + ((size_t)b * T_ + t) * S_ + s] = pr;
        }
    }
    __syncthreads();
    {   // ---- context: 2 h per thread (float2), 4-way s-ILP, len-bounded ----
        const int len4 = (len + 3) & ~3;
        const float* base = enc_out + (size_t)b * H_ + tid * 2;
        float2 ac0 = {0,0}, ac1 = {0,0}, ac2 = {0,0}, ac3 = {0,0};
        for (int s = 0; s < len4; s += 4) {
            float2 e0 = *(const float2*)(base + (size_t)(s    ) * B_ * H_);
            float2 e1 = *(const float2*)(base + (size_t)(s + 1) * B_ * H_);
            float2 e2 = *(const float2*)(base + (size_t)(s + 2) * B_ * H_);
            float2 e3 = *(const float2*)(base + (size_t)(s + 3) * B_ * H_);
            float p0 = sc[s], p1 = sc[s + 1], p2 = sc[s + 2], p3 = sc[s + 3];
            ac0.x = fmaf(p0, e0.x, ac0.x); ac0.y = fmaf(p0, e0.y, ac0.y);
            ac1.x = fmaf(p1, e1.x, ac1.x); ac1.y = fmaf(p1, e1.y, ac1.y);
            ac2.x = fmaf(p2, e2.x, ac2.x); ac2.y = fmaf(p2, e2.y, ac2.y);
            ac3.x = fmaf(p3, e3.x, ac3.x); ac3.y = fmaf(p3, e3.y, ac3.y);
        }
        comb[tid * 2 + 0] = ac0.x + ac1.x + ac2.x + ac3.x;
        comb[tid * 2 + 1] = ac0.y + ac1.y + ac2.y + ac3.y;
    }
    __syncthreads();
    {   // ---- ctx-half logits: wave wv handles v in [wv*8, wv*8+8) ----
        const float* lrow = lsrc + (size_t)b * V_;
        for (int v = wv * 8; v < wv * 8 + 8; ++v) {
            const float* w = out_W + (size_t)v * (2 * H_);
            float a0 = 0.f, a1 = 0.f;
#pragma unroll
            for (int j = 0; j < 16; j += 2) {
                a0 = fmaf(comb[lane + j * 64], w[lane + j * 64], a0);
                a1 = fmaf(comb[lane + (j + 1) * 64], w[lane + (j + 1) * 64], a1);
            }
            float acc = a0 + a1;
            for (int d = 32; d; d >>= 1) acc += __shfl_xor(acc, d);
            if (lane == 0) lg[v] = acc + lrow[v];   // lg-half incl out_b
        }
    }
    __syncthreads();
    if (wv == 0) {   // ---- softmax + renorm + argmax + stats ----
        float x = lg[lane];
        float m = x;
        for (int d = 32; d; d >>= 1) m = fmaxf(m, __shfl_xor(m, d));
        float e = expf(x - m);
        float s = e;
        for (int d = 32; d; d >>= 1) s += __shfl_xor(s, d);
        float pr = e / s;
        float ps = pr;
        for (int d = 32; d; d >>= 1) ps += __shfl_xor(ps, d);
        pr = pr / ps;   // reference renormalizes
        float bv = pr; int bi = lane;
        for (int d = 32; d; d >>= 1) {
            float ov = __shfl_xor(bv, d); int oi = __shfl_xor(bi, d);
            if (ov > bv || (ov == bv && oi < bi)) { bv = ov; bi = oi; }
        }
        float ne = pr * logf(pr + 1e-6f);
        for (int d = 32; d; d >>= 1) ne += __shfl_xor(ne, d);
        float ptok = __shfl(pr, bi);
        if (lane == 0) {
            out[t * B_ + b] = (float)bi;
            float na = negent_acc[b] + ne;                negent_acc[b] = na;
            float la = logp_acc[b] + logf(ptok + 1e-6f);  logp_acc[b] = la;
            if (t == T_ - 1) {
                out[T_ * B_ + B_ * T_ * S_ + b] = na;
                out[T_ * B_ + B_ * T_ * S_ + B_ + b] = la;
            }
            tok_s = bi;
        }
    }
    __syncthreads();
    {   // ---- value-gather next-step inputs ----
        const int tk = tok_s;
        const float* dsrc2 = dec_all + (size_t)(tk * 64 + b) * H_;
        float* dd = dec_sel + (size_t)b * H_;
        dd[tid] = dsrc2[tid];
        dd[tid + 512] = dsrc2[tid + 512];
        if (tid < V_)
            lg_sel[(size_t)b * V_ + tid] = lg_h_all[(size_t)(tk * 64 + b) * V_ + tid];
    }
}

// ------------------- fallback path kernels (validated R15) -----------------
__global__ __launch_bounds__(256) void lstm_gather_k(
    const float* __restrict__ gsrc, size_t strideB,
    const float* __restrict__ hh_gates, const float* __restrict__ enc_c0,
    float* __restrict__ out_h)
{
    int idx = blockIdx.x * 256 + threadIdx.x;
    int b = idx >> 10, h = idx & (H_ - 1);
    const float* ag = gsrc + (size_t)b * strideB;
    const float* hg = hh_gates + (size_t)b * H4_;
    float gi = ag[h]           + hg[h];
    float gf = ag[H_ + h]      + hg[H_ + h];
    float gg = ag[2 * H_ + h]  + hg[2 * H_ + h];
    float go = ag[3 * H_ + h]  + hg[3 * H_ + h];
    float cc = sigm(gf) * enc_c0[idx] + sigm(gi) * tanhf(gg);
    out_h[idx] = sigm(go) * tanhf(cc);
}

__global__ __launch_bounds__(256) void score_k(
    const float* __restrict__ enc_t, const float* __restrict__ dec_part,
    const float* __restrict__ dec_b, const float* __restrict__ attn_W,
    const float* __restrict__ attn_b, const int* __restrict__ lens,
    float* __restrict__ scores)
{
    const int lane = threadIdx.x & 63;
    const int gw = blockIdx.x * 4 + (threadIdx.x >> 6);
    const int b = gw >> 5, sg = gw & 31;
    float dec_r[16], aw_r[16];
#pragma unroll
    for (int it = 0; it < 16; ++it) {
        int h = lane + it * 64;
        dec_r[it] = dec_part[(size_t)b * H_ + h]
                  + dec_part[(size_t)(B_ + b) * H_ + h]
                  + dec_part[(size_t)(2 * B_ + b) * H_ + h]
                  + dec_part[(size_t)(3 * B_ + b) * H_ + h]
                  + dec_b[h];
        aw_r[it] = attn_W[h];
    }
    const int len = lens[b];
    const float ab = attn_b[0];
    for (int s = sg * 5; s < sg * 5 + 5; ++s) {
        if (s >= len) { if (lane == 0) scores[b * S_ + s] = -1e9f; continue; }
        const float* ep = enc_t + ((size_t)s * B_ + b) * H_;
        float acc = 0.f;
#pragma unroll
        for (int it = 0; it < 16; ++it)
            acc += aw_r[it] * tanhf(ep[lane + it * 64] + dec_r[it]);
        for (int d = 32; d; d >>= 1) acc += __shfl_xor(acc, d);
        if (lane == 0) scores[b * S_ + s] = acc + ab;
    }
}

__global__ __launch_bounds__(256) void smax_out_k(
    const float* __restrict__ scores, const float* __restrict__ enc_out,
    const float* __restrict__ out_h, const float* __restrict__ out_W,
    const float* __restrict__ out_b, const float* __restrict__ all_gates,
    const int* __restrict__ lens, float* __restrict__ gates_sel,
    float* __restrict__ negent_acc, float* __restrict__ logp_acc,
    float* __restrict__ out, int t)
{
    __shared__ float sc[S_];
    __shared__ float comb[2 * H_];
    __shared__ float lg[V_];
    __shared__ int tok_s;
    const int tid = threadIdx.x;
    const int b = blockIdx.x;
    const int lane = tid & 63, wv = tid >> 6;
    if (wv == 0) {
        float m = -1e30f;
        for (int s = lane; s < S_; s += 64) {
            float v = scores[b * S_ + s]; sc[s] = v; m = fmaxf(m, v);
        }
        for (int d = 32; d; d >>= 1) m = fmaxf(m, __shfl_xor(m, d));
        float sum = 0.f;
        for (int s = lane; s < S_; s += 64) {
            float e = expf(sc[s] - m); sc[s] = e; sum += e;
        }
        for (int d = 32; d; d >>= 1) sum += __shfl_xor(sum, d);
        float inv = 1.f / sum;
        for (int s = lane; s < S_; s += 64) {
            float pr = sc[s] * inv; sc[s] = pr;
            out[T_ * B_ + ((size_t)b * T_ + t) * S_ + s] = pr;
        }
    }
    __syncthreads();
    {
        const int len4 = (lens[b] + 3) & ~3;
        const float* base = enc_out + (size_t)b * H_ + tid * 4;
        float4 ac0 = {0,0,0,0}, ac1 = {0,0,0,0}, ac2 = {0,0,0,0}, ac3 = {0,0,0,0};
        for (int s = 0; s < len4; s += 4) {
            float4 e0 = *(const float4*)(base + (size_t)(s    ) * B_ * H_);
            float4 e1 = *(const float4*)(base + (size_t)(s + 1) * B_ * H_);
            float4 e2 = *(const float4*)(base + (size_t)(s + 2) * B_ * H_);
            float4 e3 = *(const float4*)(base + (size_t)(s + 3) * B_ * H_);
            float p0 = sc[s], p1 = sc[s + 1], p2 = sc[s + 2], p3 = sc[s + 3];
            ac0.x = fmaf(p0, e0.x, ac0.x); ac0.y = fmaf(p0, e0.y, ac0.y);
            ac0.z = fmaf(p0, e0.z, ac0.z); ac0.w = fmaf(p0, e0.w, ac0.w);
            ac1.x = fmaf(p1, e1.x, ac1.x); ac1.y = fmaf(p1, e1.y, ac1.y);
            ac1.z = fmaf(p1, e1.z, ac1.z); ac1.w = fmaf(p1, e1.w, ac1.w);
            ac2.x = fmaf(p2, e2.x, ac2.x); ac2.y = fmaf(p2, e2.y, ac2.y);
            ac2.z = fmaf(p2, e2.z, ac2.z); ac2.w = fmaf(p2, e2.w, ac2.w);
            ac3.x = fmaf(p3, e3.x, ac3.x); ac3.y = fmaf(p3, e3.y, ac3.y);
            ac3.z = fmaf(p3, e3.z, ac3.z); ac3.w = fmaf(p3, e3.w, ac3.w);
        }
        comb[tid * 4 + 0] = ac0.x + ac1.x + ac2.x + ac3.x;
        comb[tid * 4 + 1] = ac0.y + ac1.y + ac2.y + ac3.y;
        comb[tid * 4 + 2] = ac0.z + ac1.z + ac2.z + ac3.z;
        comb[tid * 4 + 3] = ac0.w + ac1.w + ac2.w + ac3.w;
    }
    for (int i = tid; i < H_; i += 256) comb[H_ + i] = out_h[(size_t)b * H_ + i];
    __syncthreads();
    for (int v = wv * 16; v < wv * 16 + 16; ++v) {
        const float* w = out_W + (size_t)v * (2 * H_);
        float a0 = 0.f, a1 = 0.f;
#pragma unroll
        for (int j = 0; j < 32; j += 2) {
            a0 = fmaf(comb[lane + j * 64], w[lane + j * 64], a0);
            a1 = fmaf(comb[lane + (j + 1) * 64], w[lane + (j + 1) * 64], a1);
        }
        float acc = a0 + a1;
        for (int d = 32; d; d >>= 1) acc += __shfl_xor(acc, d);
        if (lane == 0) lg[v] = acc + out_b[v];
    }
    __syncthreads();
    if (wv == 0) {
        float x = lg[lane];
        float m = x;
        for (int d = 32; d; d >>= 1) m = fmaxf(m, __shfl_xor(m, d));
        float e = expf(x - m);
        float s = e;
        for (int d = 32; d; d >>= 1) s += __shfl_xor(s, d);
        float pr = e / s;
        float ps = pr;
        for (int d = 32; d; d >>= 1) ps += __shfl_xor(ps, d);
        pr = pr / ps;
        float bv = pr; int bi = lane;
        for (int d = 32; d; d >>= 1) {
            float ov = __shfl_xor(bv, d); int oi = __shfl_xor(bi, d);
            if (ov > bv || (ov == bv && oi < bi)) { bv = ov; bi = oi; }
        }
        float ne = pr * logf(pr + 1e-6f);
        for (int d = 32; d; d >>= 1) ne += __shfl_xor(ne, d);
        float ptok = __shfl(pr, bi);
        if (lane == 0) {
            out[t * B_ + b] = (float)bi;
            float na = negent_acc[b] + ne;                negent_acc[b] = na;
            float la = logp_acc[b] + logf(ptok + 1e-6f);  logp_acc[b] = la;
            if (t == T_ - 1) {
                out[T_ * B_ + B_ * T_ * S_ + b] = na;
                out[T_ * B_ + B_ * T_ * S_ + B_ + b] = la;
            }
            tok_s = bi;
        }
    }
    __syncthreads();
    {
        const int tk = tok_s;
        const float4* src = (const float4*)(all_gates + (size_t)tk * H4_);
        float4* dst = (float4*)(gates_sel + (size_t)b * H4_);
        for (int i = tid; i < H4_ / 4; i += 256) dst[i] = src[i];
    }
}

extern "C" void kernel_launch(void* const* d_in, const int* in_sizes, int n_in,
                              void* d_out, int out_size, void* d_ws, size_t ws_size,
                              hipStream_t stream) {
    const float* enc_h0  = (const float*)d_in[0];
    const float* enc_c0  = (const float*)d_in[1];
    const float* enc_out = (const float*)d_in[2];
    const int*   lens    = (const int*)d_in[3];
    const float* tok_emb = (const float*)d_in[4];
    const float* embed   = (const float*)d_in[5];
    const float* W_ih    = (const float*)d_in[6];
    const float* W_hh    = (const float*)d_in[7];
    const float* b_ih    = (const float*)d_in[8];
    const float* b_hh    = (const float*)d_in[9];
    const float* out_W   = (const float*)d_in[10];
    const float* out_b   = (const float*)d_in[11];
    const float* enc_W   = (const float*)d_in[12];
    const float* enc_b   = (const float*)d_in[13];
    const float* dec_W   = (const float*)d_in[14];
    const float* dec_b   = (const float*)d_in[15];
    const float* attn_W  = (const float*)d_in[16];
    const float* attn_b  = (const float*)d_in[17];
    float* out = (float*)d_out;

    float* ws = (float*)d_ws;

    if (ws_size >= 64012800u) {
        // ---------------- fast path: 1 launch per decode step --------------
        float* hh_gates  = ws;                          // 262144
        float* dec_sel   = hh_gates + B_ * H4_;         // 65536
        float* lg_sel    = dec_sel + B_ * H_;           // 4096
        float* negent    = lg_sel + B_ * V_;            // 64
        float* logp      = negent + B_;                 // 64
        float* emb_ext   = logp + B_;                   // 65536
        float* all_gates = emb_ext + 128 * E_;          // 524288
        float* lg_h_all  = all_gates + (size_t)128 * H4_;   // 270336 (66*64*64)
        float* dec_all   = lg_h_all + (size_t)66 * 64 * V_; // 4325376
        float* enc_t     = dec_all + (size_t)66 * 64 * H_;  // 10485760
        float* outh_tmp  = enc_t;   // alias (consumed before enc_t GEMM)
        float* part      = enc_t + (size_t)66 * 64 * H_;    // alias tail? no:
        part = enc_t;   // part (hh split-K, 4*B*H4 = 1048576) also aliases enc_t
        // total = 16,003,200 floats = 64,012,800 B

        init_k<<<(128 * E_ + 255) / 256, 256, 0, stream>>>(embed, tok_emb, emb_ext,
                                                           negent, logp);
        // hh_gates (uses part alias of enc_t region, consumed immediately)
        gemm_part<<<dim3(H4_ / 64, 1, 4), 256, 0, stream>>>(enc_h0, W_hh, part, B_, H4_, H_);
        reduce_partials<<<(B_ * H4_ + 255) / 256, 256, 0, stream>>>(
            part, 4, b_ih, b_hh, hh_gates, B_ * H4_, H4_);
        // all_gates = emb_ext @ W_ih^T
        gemm_part<<<dim3(H4_ / 64, 2, 1), 256, 0, stream>>>(emb_ext, W_ih, all_gates,
                                                            128, H4_, E_);
        // out_h_all (into enc_t region) -> dec_all, lg_h_all
        outh_all_k<<<(66 * 64 * H_) / 256, 256, 0, stream>>>(all_gates, hh_gates,
                                                             enc_c0, outh_tmp);
        gemm_bt_128<<<dim3(H_ / 128, (66 * 64) / 128), 512, 0, stream>>>(
            outh_tmp, dec_W, dec_b, dec_all, 66 * 64, H_, H_);
        lgh_k<<<66, 256, 0, stream>>>(outh_tmp, out_W, out_b, lg_h_all);
        // enc_t (overwrites outh_tmp)
        gemm_bt_128<<<dim3(H_ / 128, (S_ * B_) / 128), 512, 0, stream>>>(
            enc_out, enc_W, enc_b, enc_t, S_ * B_, H_, H_);

        for (int t = 0; t < T_; ++t) {
            const float* dsrc = (t == 0) ? (dec_all + (size_t)(64 * 64) * H_) : dec_sel;
            const float* lsrc = (t == 0) ? (lg_h_all + (size_t)(64 * 64) * V_) : lg_sel;
            step_k<<<B_, 512, 0, stream>>>(enc_t, enc_out, dsrc, lsrc, attn_W, attn_b,
                                           lens, out_W, dec_all, lg_h_all, dec_sel,
                                           lg_sel, negent, logp, out, t);
        }
        return;
    }

    // ---------------- fallback path: validated round 15 ---------------------
    float* hh_gates  = ws;                         // 262144
    float* out_h     = hh_gates + B_ * H4_;        // 65536
    float* dec_part  = out_h + B_ * H_;            // 262144
    float* scores    = dec_part + 4 * B_ * H_;     // 10240
    float* negent    = scores + B_ * S_;           // 64
    float* logp      = negent + B_;                // 64
    float* gates_sel = logp + B_;                  // 262144
    float* emb_ext   = gates_sel + B_ * H4_;       // 65536
    float* all_gates = emb_ext + 128 * E_;         // 524288
    float* enc_t     = all_gates + (size_t)128 * H4_;  // 10485760
    float* part      = enc_t;
    if (ws_size < 47751680u) return;

    init_k<<<(128 * E_ + 255) / 256, 256, 0, stream>>>(embed, tok_emb, emb_ext,
                                                       negent, logp);
    gemm_part<<<dim3(H4_ / 64, 1, 4), 256, 0, stream>>>(enc_h0, W_hh, part, B_, H4_, H_);
    reduce_partials<<<(B_ * H4_ + 255) / 256, 256, 0, stream>>>(
        part, 4, b_ih, b_hh, hh_gates, B_ * H4_, H4_);
    gemm_part<<<dim3(H4_ / 64, 2, 1), 256, 0, stream>>>(emb_ext, W_ih, all_gates,
                                                        128, H4_, E_);
    gemm_bt_128<<<dim3(H_ / 128, (S_ * B_) / 128), 512, 0, stream>>>(
        enc_out, enc_W, enc_b, enc_t, S_ * B_, H_, H_);

    for (int t = 0; t < T_; ++t) {
        const float* gsrc = (t == 0) ? (all_gates + (size_t)64 * H4_) : gates_sel;
        const size_t strideB = (t == 0) ? 0 : (size_t)H4_;
        lstm_gather_k<<<(B_ * H_) / 256, 256, 0, stream>>>(gsrc, strideB, hh_gates,
                                                           enc_c0, out_h);
        gemm_part<<<dim3(H_ / 64, 1, 4), 256, 0, stream>>>(out_h, dec_W, dec_part, B_, H_, H_);
        score_k<<<512, 256, 0, stream>>>(enc_t, dec_part, dec_b, attn_W, attn_b, lens, scores);
        smax_out_k<<<64, 256, 0, stream>>>(scores, enc_out, out_h, out_W, out_b,
                                           all_gates, lens, gates_sel, negent, logp, out, t);
    }
}

// Round 17
// 1522.859 us; speedup vs baseline: 1.9255x; 1.9255x over previous
//
#include <hip/hip_runtime.h>

#define S_ 160
#define B_ 64
#define H_ 1024
#define E_ 512
#define V_ 64
#define T_ 16
#define H4_ 4096

__device__ __forceinline__ float sigm(float x) { return 1.f / (1.f + expf(-x)); }

// ---------------------------------------------------------------------------
// C = A @ Bm^T + bias. 128x128 tile, BK=16, 512 threads, 4x8 acc/thread.
// (validated round 15/16)
// ---------------------------------------------------------------------------
__global__ __launch_bounds__(512) void gemm_bt_128(
    const float* __restrict__ A, const float* __restrict__ Bm,
    const float* __restrict__ bias, float* __restrict__ Cd,
    int M, int N, int K)
{
    __shared__ float As[16][132];
    __shared__ float Bs[16][132];
    const int bn = blockIdx.x, bm = blockIdx.y;
    const int tid = threadIdx.x;
    const int lr = tid >> 2, lk = (tid & 3) * 4;
    const int cx4 = (tid & 15) * 4, ry4 = (tid >> 4) * 4;
    const float* Ap = A + (size_t)(bm * 128 + lr) * K + lk;
    const float* Bp = Bm + (size_t)(bn * 128 + lr) * K + lk;
    float acc[4][8] = {};
    for (int k0 = 0; k0 < K; k0 += 16) {
        float4 av = *(const float4*)(Ap + k0);
        float4 bv = *(const float4*)(Bp + k0);
        __syncthreads();
        As[lk + 0][lr] = av.x; As[lk + 1][lr] = av.y;
        As[lk + 2][lr] = av.z; As[lk + 3][lr] = av.w;
        Bs[lk + 0][lr] = bv.x; Bs[lk + 1][lr] = bv.y;
        Bs[lk + 2][lr] = bv.z; Bs[lk + 3][lr] = bv.w;
        __syncthreads();
#pragma unroll
        for (int kk = 0; kk < 16; ++kk) {
            float a[4], b[8];
            *(float4*)(a)     = *(const float4*)&As[kk][ry4];
            *(float4*)(b)     = *(const float4*)&Bs[kk][cx4];
            *(float4*)(b + 4) = *(const float4*)&Bs[kk][64 + cx4];
#pragma unroll
            for (int i = 0; i < 4; ++i)
#pragma unroll
                for (int j = 0; j < 8; ++j) acc[i][j] = fmaf(a[i], b[j], acc[i][j]);
        }
    }
#pragma unroll
    for (int i = 0; i < 4; ++i) {
        int row = bm * 128 + ry4 + i;
#pragma unroll
        for (int j = 0; j < 8; ++j) {
            int col = bn * 128 + ((j < 4) ? (cx4 + j) : (64 + cx4 + j - 4));
            Cd[(size_t)row * N + col] = acc[i][j] + bias[col];
        }
    }
}

// 64x64 tile GEMM helper (BK=16). Strides baked into Arow/Brow pointers.
__device__ __forceinline__ void tile64(const float* __restrict__ Arow,
                                       const float* __restrict__ Brow,
                                       int K, float acc[4][4],
                                       float* __restrict__ As,
                                       float* __restrict__ Bs)
{
    const int tid = threadIdx.x;
    const int lr = tid >> 2, lc = (tid & 3) << 2;
    const int tx = tid & 15, ty = tid >> 4;
    for (int k0 = 0; k0 < K; k0 += 16) {
        float4 av = *(const float4*)(Arow + k0);
        float4 bv = *(const float4*)(Brow + k0);
        __syncthreads();
        As[lr * 17 + lc + 0] = av.x; As[lr * 17 + lc + 1] = av.y;
        As[lr * 17 + lc + 2] = av.z; As[lr * 17 + lc + 3] = av.w;
        Bs[lr * 17 + lc + 0] = bv.x; Bs[lr * 17 + lc + 1] = bv.y;
        Bs[lr * 17 + lc + 2] = bv.z; Bs[lr * 17 + lc + 3] = bv.w;
        __syncthreads();
#pragma unroll
        for (int kk = 0; kk < 16; ++kk) {
            float a[4], b[4];
#pragma unroll
            for (int i = 0; i < 4; ++i) a[i] = As[(ty * 4 + i) * 17 + kk];
#pragma unroll
            for (int j = 0; j < 4; ++j) b[j] = Bs[(tx * 4 + j) * 17 + kk];
#pragma unroll
            for (int i = 0; i < 4; ++i)
#pragma unroll
                for (int j = 0; j < 4; ++j) acc[i][j] = fmaf(a[i], b[j], acc[i][j]);
        }
    }
    __syncthreads();
}

// Split-K partials: Cpart[kz][M][N]. KS==1 -> plain GEMM to Cpart.
__global__ __launch_bounds__(256) void gemm_part(
    const float* __restrict__ A, const float* __restrict__ Bm,
    float* __restrict__ Cpart, int M, int N, int K)
{
    __shared__ float smem[2176];
    const int bn = blockIdx.x, bm = blockIdx.y, kz = blockIdx.z, KS = gridDim.z;
    const int tid = threadIdx.x;
    const int lr = tid >> 2, lc = (tid & 3) << 2;
    const int tx = tid & 15, ty = tid >> 4;
    const int kLen = K / KS, k0base = kz * kLen;
    float acc[4][4] = {};
    tile64(A + (size_t)(bm * 64 + lr) * K + k0base + lc,
           Bm + (size_t)(bn * 64 + lr) * K + k0base + lc,
           kLen, acc, smem, smem + 1088);
    float* Cp = Cpart + (size_t)kz * M * N;
#pragma unroll
    for (int i = 0; i < 4; ++i) {
        int row = bm * 64 + ty * 4 + i;
#pragma unroll
        for (int j = 0; j < 4; ++j)
            Cp[(size_t)row * N + bn * 64 + tx * 4 + j] = acc[i][j];
    }
}

__global__ void reduce_partials(const float* __restrict__ Cpart, int KS,
                                const float* __restrict__ bias,
                                const float* __restrict__ bias2,
                                float* __restrict__ C, int MN, int N)
{
    int idx = blockIdx.x * 256 + threadIdx.x;
    if (idx >= MN) return;
    float v = 0.f;
    for (int z = 0; z < KS; ++z) v += Cpart[(size_t)z * MN + idx];
    int col = idx % N;
    if (bias)  v += bias[col];
    if (bias2) v += bias2[col];
    C[idx] = v;
}

// emb_ext rows 0..63 = embed, 64 = tok_emb(SOS), 65..127 = 0; zero accums.
__global__ void init_k(const float* __restrict__ embed, const float* __restrict__ tok_emb,
                       float* __restrict__ emb_ext,
                       float* __restrict__ negent, float* __restrict__ logp)
{
    int i = blockIdx.x * 256 + threadIdx.x;
    if (i < 128 * E_) {
        int r = i >> 9, c = i & (E_ - 1);
        emb_ext[i] = (r < 64) ? embed[r * E_ + c] : ((r == 64) ? tok_emb[c] : 0.f);
    }
    if (i < B_) { negent[i] = 0.f; logp[i] = 0.f; }
}

// out_h_all[(v*64+b)][h] = LSTM(all_gates[v] + hh_gates[b]), v<66 b<64.
__global__ __launch_bounds__(256) void outh_all_k(
    const float* __restrict__ all_gates, const float* __restrict__ hh_gates,
    const float* __restrict__ enc_c0, float* __restrict__ outh)
{
    size_t idx = (size_t)blockIdx.x * 256 + threadIdx.x;
    int row = (int)(idx >> 10), h = (int)(idx & (H_ - 1));
    int v = row >> 6, b = row & 63;
    const float* ag = all_gates + (size_t)v * H4_;
    const float* hg = hh_gates + (size_t)b * H4_;
    float gi = ag[h]          + hg[h];
    float gf = ag[H_ + h]     + hg[H_ + h];
    float gg = ag[2 * H_ + h] + hg[2 * H_ + h];
    float go = ag[3 * H_ + h] + hg[3 * H_ + h];
    float cc = sigm(gf) * enc_c0[(size_t)b * H_ + h] + sigm(gi) * tanhf(gg);
    outh[idx] = sigm(go) * tanhf(cc);
}

// lg_h_all[row][v] = out_h_all[row] . out_W[v][H:2H] + out_b[v].  66 blocks.
__global__ __launch_bounds__(256) void lgh_k(
    const float* __restrict__ outh, const float* __restrict__ out_W,
    const float* __restrict__ out_b, float* __restrict__ lgh)
{
    __shared__ float smem[2176];
    const int bm = blockIdx.x;
    const int tid = threadIdx.x;
    const int lr = tid >> 2, lc = (tid & 3) << 2;
    const int tx = tid & 15, ty = tid >> 4;
    float acc[4][4] = {};
    tile64(outh + (size_t)(bm * 64 + lr) * H_ + lc,
           out_W + (size_t)lr * (2 * H_) + H_ + lc,
           H_, acc, smem, smem + 1088);
#pragma unroll
    for (int i = 0; i < 4; ++i) {
        int row = bm * 64 + ty * 4 + i;
#pragma unroll
        for (int j = 0; j < 4; ++j) {
            int col = tx * 4 + j;
            lgh[(size_t)row * V_ + col] = acc[i][j] + out_b[col];
        }
    }
}

// ---------------------------------------------------------------------------
// Scores, WIDE: 512 blocks x 4 waves = 2048 waves; wave (b, sg) does 5 s.
// dec_r read directly from dsrc (includes dec_b via GEMM bias).
// ---------------------------------------------------------------------------
__global__ __launch_bounds__(256) void score_k2(
    const float* __restrict__ enc_t, const float* __restrict__ dsrc,
    const float* __restrict__ attn_W, const float* __restrict__ attn_b,
    const int* __restrict__ lens, float* __restrict__ scores)
{
    const int lane = threadIdx.x & 63;
    const int gw = blockIdx.x * 4 + (threadIdx.x >> 6);   // 0..2047
    const int b = gw >> 5, sg = gw & 31;                  // 32 waves/b, 5 s each
    float dec_r[16], aw_r[16];
    const float* dr = dsrc + (size_t)b * H_;
#pragma unroll
    for (int it = 0; it < 16; ++it) {
        int h = lane + it * 64;
        dec_r[it] = dr[h];
        aw_r[it] = attn_W[h];
    }
    const int len = lens[b];
    const float ab = attn_b[0];
    for (int s = sg * 5; s < sg * 5 + 5; ++s) {
        if (s >= len) { if (lane == 0) scores[b * S_ + s] = -1e9f; continue; }
        const float* ep = enc_t + ((size_t)s * B_ + b) * H_;
        float acc = 0.f;
#pragma unroll
        for (int it = 0; it < 16; ++it)
            acc += aw_r[it] * tanhf(ep[lane + it * 64] + dec_r[it]);
        for (int d = 32; d; d >>= 1) acc += __shfl_xor(acc, d);
        if (lane == 0) scores[b * S_ + s] = acc + ab;
    }
}

// ---------------------------------------------------------------------------
// Tail: softmax + attn-out + context (float4, len-bounded) + ctx-half logits
// (+ precomputed lg-half) + renorm/argmax/stats + value-gather next
// dec_sel/lg_sel. One block per b x 256 threads.
// ---------------------------------------------------------------------------
__global__ __launch_bounds__(256) void smax_out2_k(
    const float* __restrict__ scores, const float* __restrict__ enc_out,
    const float* __restrict__ out_W, const float* __restrict__ lsrc,
    const int* __restrict__ lens,
    const float* __restrict__ dec_all, const float* __restrict__ lg_h_all,
    float* __restrict__ dec_sel, float* __restrict__ lg_sel,
    float* __restrict__ negent_acc, float* __restrict__ logp_acc,
    float* __restrict__ out, int t)
{
    __shared__ float sc[S_];
    __shared__ float comb[H_];
    __shared__ float lg[V_];
    __shared__ int tok_s;
    const int tid = threadIdx.x;
    const int b = blockIdx.x;
    const int lane = tid & 63, wv = tid >> 6;
    if (wv == 0) {
        float m = -1e30f;
        for (int s = lane; s < S_; s += 64) {
            float v = scores[b * S_ + s]; sc[s] = v; m = fmaxf(m, v);
        }
        for (int d = 32; d; d >>= 1) m = fmaxf(m, __shfl_xor(m, d));
        float sum = 0.f;
        for (int s = lane; s < S_; s += 64) {
            float e = expf(sc[s] - m); sc[s] = e; sum += e;
        }
        for (int d = 32; d; d >>= 1) sum += __shfl_xor(sum, d);
        float inv = 1.f / sum;
        for (int s = lane; s < S_; s += 64) {
            float pr = sc[s] * inv; sc[s] = pr;
            out[T_ * B_ + ((size_t)b * T_ + t) * S_ + s] = pr;
        }
    }
    __syncthreads();
    {   // context: 4 h per thread, float4, 4-way s-ILP, len-bounded
        const int len4 = (lens[b] + 3) & ~3;
        const float* base = enc_out + (size_t)b * H_ + tid * 4;
        float4 ac0 = {0,0,0,0}, ac1 = {0,0,0,0}, ac2 = {0,0,0,0}, ac3 = {0,0,0,0};
        for (int s = 0; s < len4; s += 4) {
            float4 e0 = *(const float4*)(base + (size_t)(s    ) * B_ * H_);
            float4 e1 = *(const float4*)(base + (size_t)(s + 1) * B_ * H_);
            float4 e2 = *(const float4*)(base + (size_t)(s + 2) * B_ * H_);
            float4 e3 = *(const float4*)(base + (size_t)(s + 3) * B_ * H_);
            float p0 = sc[s], p1 = sc[s + 1], p2 = sc[s + 2], p3 = sc[s + 3];
            ac0.x = fmaf(p0, e0.x, ac0.x); ac0.y = fmaf(p0, e0.y, ac0.y);
            ac0.z = fmaf(p0, e0.z, ac0.z); ac0.w = fmaf(p0, e0.w, ac0.w);
            ac1.x = fmaf(p1, e1.x, ac1.x); ac1.y = fmaf(p1, e1.y, ac1.y);
            ac1.z = fmaf(p1, e1.z, ac1.z); ac1.w = fmaf(p1, e1.w, ac1.w);
            ac2.x = fmaf(p2, e2.x, ac2.x); ac2.y = fmaf(p2, e2.y, ac2.y);
            ac2.z = fmaf(p2, e2.z, ac2.z); ac2.w = fmaf(p2, e2.w, ac2.w);
            ac3.x = fmaf(p3, e3.x, ac3.x); ac3.y = fmaf(p3, e3.y, ac3.y);
            ac3.z = fmaf(p3, e3.z, ac3.z); ac3.w = fmaf(p3, e3.w, ac3.w);
        }
        comb[tid * 4 + 0] = ac0.x + ac1.x + ac2.x + ac3.x;
        comb[tid * 4 + 1] = ac0.y + ac1.y + ac2.y + ac3.y;
        comb[tid * 4 + 2] = ac0.z + ac1.z + ac2.z + ac3.z;
        comb[tid * 4 + 3] = ac0.w + ac1.w + ac2.w + ac3.w;
    }
    __syncthreads();
    for (int v = wv * 16; v < wv * 16 + 16; ++v) {   // ctx-half logits (K=H)
        const float* w = out_W + (size_t)v * (2 * H_);
        float a0 = 0.f, a1 = 0.f;
#pragma unroll
        for (int j = 0; j < 16; j += 2) {
            a0 = fmaf(comb[lane + j * 64], w[lane + j * 64], a0);
            a1 = fmaf(comb[lane + (j + 1) * 64], w[lane + (j + 1) * 64], a1);
        }
        float acc = a0 + a1;
        for (int d = 32; d; d >>= 1) acc += __shfl_xor(acc, d);
        if (lane == 0) lg[v] = acc + lsrc[(size_t)b * V_ + v];
    }
    __syncthreads();
    if (wv == 0) {
        float x = lg[lane];
        float m = x;
        for (int d = 32; d; d >>= 1) m = fmaxf(m, __shfl_xor(m, d));
        float e = expf(x - m);
        float s = e;
        for (int d = 32; d; d >>= 1) s += __shfl_xor(s, d);
        float pr = e / s;
        float ps = pr;
        for (int d = 32; d; d >>= 1) ps += __shfl_xor(ps, d);
        pr = pr / ps;   // reference renormalizes
        float bv = pr; int bi = lane;
        for (int d = 32; d; d >>= 1) {
            float ov = __shfl_xor(bv, d); int oi = __shfl_xor(bi, d);
            if (ov > bv || (ov == bv && oi < bi)) { bv = ov; bi = oi; }
        }
        float ne = pr * logf(pr + 1e-6f);
        for (int d = 32; d; d >>= 1) ne += __shfl_xor(ne, d);
        float ptok = __shfl(pr, bi);
        if (lane == 0) {
            out[t * B_ + b] = (float)bi;
            float na = negent_acc[b] + ne;                negent_acc[b] = na;
            float la = logp_acc[b] + logf(ptok + 1e-6f);  logp_acc[b] = la;
            if (t == T_ - 1) {
                out[T_ * B_ + B_ * T_ * S_ + b] = na;
                out[T_ * B_ + B_ * T_ * S_ + B_ + b] = la;
            }
            tok_s = bi;
        }
    }
    __syncthreads();
    {   // value-gather next-step inputs (R12-proven pattern)
        const int tk = tok_s;
        const float4* src = (const float4*)(dec_all + (size_t)(tk * 64 + b) * H_);
        float4* dst = (float4*)(dec_sel + (size_t)b * H_);
        dst[tid] = src[tid];                     // 256 x float4 = 1024 floats
        if (tid < V_)
            lg_sel[(size_t)b * V_ + tid] = lg_h_all[(size_t)(tk * 64 + b) * V_ + tid];
    }
}

// ------------------- fallback path kernels (validated R15) -----------------
__global__ __launch_bounds__(256) void lstm_gather_k(
    const float* __restrict__ gsrc, size_t strideB,
    const float* __restrict__ hh_gates, const float* __restrict__ enc_c0,
    float* __restrict__ out_h)
{
    int idx = blockIdx.x * 256 + threadIdx.x;
    int b = idx >> 10, h = idx & (H_ - 1);
    const float* ag = gsrc + (size_t)b * strideB;
    const float* hg = hh_gates + (size_t)b * H4_;
    float gi = ag[h]           + hg[h];
    float gf = ag[H_ + h]      + hg[H_ + h];
    float gg = ag[2 * H_ + h]  + hg[2 * H_ + h];
    float go = ag[3 * H_ + h]  + hg[3 * H_ + h];
    float cc = sigm(gf) * enc_c0[idx] + sigm(gi) * tanhf(gg);
    out_h[idx] = sigm(go) * tanhf(cc);
}

__global__ __launch_bounds__(256) void score_k(
    const float* __restrict__ enc_t, const float* __restrict__ dec_part,
    const float* __restrict__ dec_b, const float* __restrict__ attn_W,
    const float* __restrict__ attn_b, const int* __restrict__ lens,
    float* __restrict__ scores)
{
    const int lane = threadIdx.x & 63;
    const int gw = blockIdx.x * 4 + (threadIdx.x >> 6);
    const int b = gw >> 5, sg = gw & 31;
    float dec_r[16], aw_r[16];
#pragma unroll
    for (int it = 0; it < 16; ++it) {
        int h = lane + it * 64;
        dec_r[it] = dec_part[(size_t)b * H_ + h]
                  + dec_part[(size_t)(B_ + b) * H_ + h]
                  + dec_part[(size_t)(2 * B_ + b) * H_ + h]
                  + dec_part[(size_t)(3 * B_ + b) * H_ + h]
                  + dec_b[h];
        aw_r[it] = attn_W[h];
    }
    const int len = lens[b];
    const float ab = attn_b[0];
    for (int s = sg * 5; s < sg * 5 + 5; ++s) {
        if (s >= len) { if (lane == 0) scores[b * S_ + s] = -1e9f; continue; }
        const float* ep = enc_t + ((size_t)s * B_ + b) * H_;
        float acc = 0.f;
#pragma unroll
        for (int it = 0; it < 16; ++it)
            acc += aw_r[it] * tanhf(ep[lane + it * 64] + dec_r[it]);
        for (int d = 32; d; d >>= 1) acc += __shfl_xor(acc, d);
        if (lane == 0) scores[b * S_ + s] = acc + ab;
    }
}

__global__ __launch_bounds__(256) void smax_out_k(
    const float* __restrict__ scores, const float* __restrict__ enc_out,
    const float* __restrict__ out_h, const float* __restrict__ out_W,
    const float* __restrict__ out_b, const float* __restrict__ all_gates,
    const int* __restrict__ lens, float* __restrict__ gates_sel,
    float* __restrict__ negent_acc, float* __restrict__ logp_acc,
    float* __restrict__ out, int t)
{
    __shared__ float sc[S_];
    __shared__ float comb[2 * H_];
    __shared__ float lg[V_];
    __shared__ int tok_s;
    const int tid = threadIdx.x;
    const int b = blockIdx.x;
    const int lane = tid & 63, wv = tid >> 6;
    if (wv == 0) {
        float m = -1e30f;
        for (int s = lane; s < S_; s += 64) {
            float v = scores[b * S_ + s]; sc[s] = v; m = fmaxf(m, v);
        }
        for (int d = 32; d; d >>= 1) m = fmaxf(m, __shfl_xor(m, d));
        float sum = 0.f;
        for (int s = lane; s < S_; s += 64) {
            float e = expf(sc[s] - m); sc[s] = e; sum += e;
        }
        for (int d = 32; d; d >>= 1) sum += __shfl_xor(sum, d);
        float inv = 1.f / sum;
        for (int s = lane; s < S_; s += 64) {
            float pr = sc[s] * inv; sc[s] = pr;
            out[T_ * B_ + ((size_t)b * T_ + t) * S_ + s] = pr;
        }
    }
    __syncthreads();
    {
        const int len4 = (lens[b] + 3) & ~3;
        const float* base = enc_out + (size_t)b * H_ + tid * 4;
        float4 ac0 = {0,0,0,0}, ac1 = {0,0,0,0}, ac2 = {0,0,0,0}, ac3 = {0,0,0,0};
        for (int s = 0; s < len4; s += 4) {
            float4 e0 = *(const float4*)(base + (size_t)(s    ) * B_ * H_);
            float4 e1 = *(const float4*)(base + (size_t)(s + 1) * B_ * H_);
            float4 e2 = *(const float4*)(base + (size_t)(s + 2) * B_ * H_);
            float4 e3 = *(const float4*)(base + (size_t)(s + 3) * B_ * H_);
            float p0 = sc[s], p1 = sc[s + 1], p2 = sc[s + 2], p3 = sc[s + 3];
            ac0.x = fmaf(p0, e0.x, ac0.x); ac0.y = fmaf(p0, e0.y, ac0.y);
            ac0.z = fmaf(p0, e0.z, ac0.z); ac0.w = fmaf(p0, e0.w, ac0.w);
            ac1.x = fmaf(p1, e1.x, ac1.x); ac1.y = fmaf(p1, e1.y, ac1.y);
            ac1.z = fmaf(p1, e1.z, ac1.z); ac1.w = fmaf(p1, e1.w, ac1.w);
            ac2.x = fmaf(p2, e2.x, ac2.x); ac2.y = fmaf(p2, e2.y, ac2.y);
            ac2.z = fmaf(p2, e2.z, ac2.z); ac2.w = fmaf(p2, e2.w, ac2.w);
            ac3.x = fmaf(p3, e3.x, ac3.x); ac3.y = fmaf(p3, e3.y, ac3.y);
            ac3.z = fmaf(p3, e3.z, ac3.z); ac3.w = fmaf(p3, e3.w, ac3.w);
        }
        comb[tid * 4 + 0] = ac0.x + ac1.x + ac2.x + ac3.x;
        comb[tid * 4 + 1] = ac0.y + ac1.y + ac2.y + ac3.y;
        comb[tid * 4 + 2] = ac0.z + ac1.z + ac2.z + ac3.z;
        comb[tid * 4 + 3] = ac0.w + ac1.w + ac2.w + ac3.w;
    }
    for (int i = tid; i < H_; i += 256) comb[H_ + i] = out_h[(size_t)b * H_ + i];
    __syncthreads();
    for (int v = wv * 16; v < wv * 16 + 16; ++v) {
        const float* w = out_W + (size_t)v * (2 * H_);
        float a0 = 0.f, a1 = 0.f;
#pragma unroll
        for (int j = 0; j < 32; j += 2) {
            a0 = fmaf(comb[lane + j * 64], w[lane + j * 64], a0);
            a1 = fmaf(comb[lane + (j + 1) * 64], w[lane + (j + 1) * 64], a1);
        }
        float acc = a0 + a1;
        for (int d = 32; d; d >>= 1) acc += __shfl_xor(acc, d);
        if (lane == 0) lg[v] = acc + out_b[v];
    }
    __syncthreads();
    if (wv == 0) {
        float x = lg[lane];
        float m = x;
        for (int d = 32; d; d >>= 1) m = fmaxf(m, __shfl_xor(m, d));
        float e = expf(x - m);
        float s = e;
        for (int d = 32; d; d >>= 1) s += __shfl_xor(s, d);
        float pr = e / s;
        float ps = pr;
        for (int d = 32; d; d >>= 1) ps += __shfl_xor(ps, d);
        pr = pr / ps;
        float bv = pr; int bi = lane;
        for (int d = 32; d; d >>= 1) {
            float ov = __shfl_xor(bv, d); int oi = __shfl_xor(bi, d);
            if (ov > bv || (ov == bv && oi < bi)) { bv = ov; bi = oi; }
        }
        float ne = pr * logf(pr + 1e-6f);
        for (int d = 32; d; d >>= 1) ne += __shfl_xor(ne, d);
        float ptok = __shfl(pr, bi);
        if (lane == 0) {
            out[t * B_ + b] = (float)bi;
            float na = negent_acc[b] + ne;                negent_acc[b] = na;
            float la = logp_acc[b] + logf(ptok + 1e-6f);  logp_acc[b] = la;
            if (t == T_ - 1) {
                out[T_ * B_ + B_ * T_ * S_ + b] = na;
                out[T_ * B_ + B_ * T_ * S_ + B_ + b] = la;
            }
            tok_s = bi;
        }
    }
    __syncthreads();
    {
        const int tk = tok_s;
        const float4* src = (const float4*)(all_gates + (size_t)tk * H4_);
        float4* dst = (float4*)(gates_sel + (size_t)b * H4_);
        for (int i = tid; i < H4_ / 4; i += 256) dst[i] = src[i];
    }
}

extern "C" void kernel_launch(void* const* d_in, const int* in_sizes, int n_in,
                              void* d_out, int out_size, void* d_ws, size_t ws_size,
                              hipStream_t stream) {
    const float* enc_h0  = (const float*)d_in[0];
    const float* enc_c0  = (const float*)d_in[1];
    const float* enc_out = (const float*)d_in[2];
    const int*   lens    = (const int*)d_in[3];
    const float* tok_emb = (const float*)d_in[4];
    const float* embed   = (const float*)d_in[5];
    const float* W_ih    = (const float*)d_in[6];
    const float* W_hh    = (const float*)d_in[7];
    const float* b_ih    = (const float*)d_in[8];
    const float* b_hh    = (const float*)d_in[9];
    const float* out_W   = (const float*)d_in[10];
    const float* out_b   = (const float*)d_in[11];
    const float* enc_W   = (const float*)d_in[12];
    const float* enc_b   = (const float*)d_in[13];
    const float* dec_W   = (const float*)d_in[14];
    const float* dec_b   = (const float*)d_in[15];
    const float* attn_W  = (const float*)d_in[16];
    const float* attn_b  = (const float*)d_in[17];
    float* out = (float*)d_out;

    float* ws = (float*)d_ws;

    if (ws_size >= 64012800u) {
        // -------- fast path: dec/lg precompute, 2 launches per step --------
        float* hh_gates  = ws;                          // 262144
        float* dec_sel   = hh_gates + B_ * H4_;         // 65536
        float* lg_sel    = dec_sel + B_ * H_;           // 4096
        float* negent    = lg_sel + B_ * V_;            // 64
        float* logp      = negent + B_;                 // 64
        float* emb_ext   = logp + B_;                   // 65536
        float* all_gates = emb_ext + 128 * E_;          // 524288
        float* lg_h_all  = all_gates + (size_t)128 * H4_;   // 270336
        float* dec_all   = lg_h_all + (size_t)66 * 64 * V_; // 4325376
        float* enc_t     = dec_all + (size_t)66 * 64 * H_;  // 10485760
        float* outh_tmp  = enc_t;   // alias (consumed before enc_t GEMM)
        float* part      = enc_t;   // alias (consumed before enc_t GEMM)
        float* scores    = dec_sel; // scores[B*S] aliases nothing live? no:
        // scores must not alias dec_sel (both live in a step). Use tail:
        scores = enc_t + (size_t)S_ * B_ * H_ - B_ * S_;  // last 10240 of ws
        // enc_t region is 10485760; enc_t GEMM writes all of it. scores sits
        // past enc_t? No -- place scores in its own slot instead:
        // (we have headroom: total below = 64,012,800 B exactly; reuse
        //  emb_ext (65536 floats, dead after all_gates GEMM) for scores.)
        scores = emb_ext;   // dead after setup; B*S = 10240 fits

        init_k<<<(128 * E_ + 255) / 256, 256, 0, stream>>>(embed, tok_emb, emb_ext,
                                                           negent, logp);
        gemm_part<<<dim3(H4_ / 64, 1, 4), 256, 0, stream>>>(enc_h0, W_hh, part, B_, H4_, H_);
        reduce_partials<<<(B_ * H4_ + 255) / 256, 256, 0, stream>>>(
            part, 4, b_ih, b_hh, hh_gates, B_ * H4_, H4_);
        gemm_part<<<dim3(H4_ / 64, 2, 1), 256, 0, stream>>>(emb_ext, W_ih, all_gates,
                                                            128, H4_, E_);
        outh_all_k<<<(66 * 64 * H_) / 256, 256, 0, stream>>>(all_gates, hh_gates,
                                                             enc_c0, outh_tmp);
        gemm_bt_128<<<dim3(H_ / 128, (66 * 64) / 128), 512, 0, stream>>>(
            outh_tmp, dec_W, dec_b, dec_all, 66 * 64, H_, H_);
        lgh_k<<<66, 256, 0, stream>>>(outh_tmp, out_W, out_b, lg_h_all);
        gemm_bt_128<<<dim3(H_ / 128, (S_ * B_) / 128), 512, 0, stream>>>(
            enc_out, enc_W, enc_b, enc_t, S_ * B_, H_, H_);

        for (int t = 0; t < T_; ++t) {
            const float* dsrc = (t == 0) ? (dec_all + (size_t)(64 * 64) * H_) : dec_sel;
            const float* lsrc = (t == 0) ? (lg_h_all + (size_t)(64 * 64) * V_) : lg_sel;
            score_k2<<<512, 256, 0, stream>>>(enc_t, dsrc, attn_W, attn_b, lens, scores);
            smax_out2_k<<<B_, 256, 0, stream>>>(scores, enc_out, out_W, lsrc, lens,
                                                dec_all, lg_h_all, dec_sel, lg_sel,
                                                negent, logp, out, t);
        }
        return;
    }

    // ---------------- fallback path: validated round 15 ---------------------
    float* hh_gates  = ws;                         // 262144
    float* out_h     = hh_gates + B_ * H4_;        // 65536
    float* dec_part  = out_h + B_ * H_;            // 262144
    float* scores    = dec_part + 4 * B_ * H_;     // 10240
    float* negent    = scores + B_ * S_;           // 64
    float* logp      = negent + B_;                // 64
    float* gates_sel = logp + B_;                  // 262144
    float* emb_ext   = gates_sel + B_ * H4_;       // 65536
    float* all_gates = emb_ext + 128 * E_;         // 524288
    float* enc_t     = all_gates + (size_t)128 * H4_;  // 10485760
    float* part      = enc_t;
    if (ws_size < 47751680u) return;

    init_k<<<(128 * E_ + 255) / 256, 256, 0, stream>>>(embed, tok_emb, emb_ext,
                                                       negent, logp);
    gemm_part<<<dim3(H4_ / 64, 1, 4), 256, 0, stream>>>(enc_h0, W_hh, part, B_, H4_, H_);
    reduce_partials<<<(B_ * H4_ + 255) / 256, 256, 0, stream>>>(
        part, 4, b_ih, b_hh, hh_gates, B_ * H4_, H4_);
    gemm_part<<<dim3(H4_ / 64, 2, 1), 256, 0, stream>>>(emb_ext, W_ih, all_gates,
                                                        128, H4_, E_);
    gemm_bt_128<<<dim3(H_ / 128, (S_ * B_) / 128), 512, 0, stream>>>(
        enc_out, enc_W, enc_b, enc_t, S_ * B_, H_, H_);

    for (int t = 0; t < T_; ++t) {
        const float* gsrc = (t == 0) ? (all_gates + (size_t)64 * H4_) : gates_sel;
        const size_t strideB = (t == 0) ? 0 : (size_t)H4_;
        lstm_gather_k<<<(B_ * H_) / 256, 256, 0, stream>>>(gsrc, strideB, hh_gates,
                                                           enc_c0, out_h);
        gemm_part<<<dim3(H_ / 64, 1, 4), 256, 0, stream>>>(out_h, dec_W, dec_part, B_, H_, H_);
        score_k<<<512, 256, 0, stream>>>(enc_t, dec_part, dec_b, attn_W, attn_b, lens, scores);
        smax_out_k<<<64, 256, 0, stream>>>(scores, enc_out, out_h, out_W, out_b,
                                           all_gates, lens, gates_sel, negent, logp, out, t);
    }
}

// Round 18
// 1498.510 us; speedup vs baseline: 1.9568x; 1.0162x over previous
//
#include <hip/hip_runtime.h>

#define S_ 160
#define B_ 64
#define H_ 1024
#define E_ 512
#define V_ 64
#define T_ 16
#define H4_ 4096

__device__ __forceinline__ float sigm(float x) { return 1.f / (1.f + expf(-x)); }

// ---------------------------------------------------------------------------
// C = A @ Bm^T + bias. 128x128 tile, BK=16, 512 threads, 4x8 acc/thread.
// (validated rounds 15-17)
// ---------------------------------------------------------------------------
__global__ __launch_bounds__(512) void gemm_bt_128(
    const float* __restrict__ A, const float* __restrict__ Bm,
    const float* __restrict__ bias, float* __restrict__ Cd,
    int M, int N, int K)
{
    __shared__ float As[16][132];
    __shared__ float Bs[16][132];
    const int bn = blockIdx.x, bm = blockIdx.y;
    const int tid = threadIdx.x;
    const int lr = tid >> 2, lk = (tid & 3) * 4;
    const int cx4 = (tid & 15) * 4, ry4 = (tid >> 4) * 4;
    const float* Ap = A + (size_t)(bm * 128 + lr) * K + lk;
    const float* Bp = Bm + (size_t)(bn * 128 + lr) * K + lk;
    float acc[4][8] = {};
    for (int k0 = 0; k0 < K; k0 += 16) {
        float4 av = *(const float4*)(Ap + k0);
        float4 bv = *(const float4*)(Bp + k0);
        __syncthreads();
        As[lk + 0][lr] = av.x; As[lk + 1][lr] = av.y;
        As[lk + 2][lr] = av.z; As[lk + 3][lr] = av.w;
        Bs[lk + 0][lr] = bv.x; Bs[lk + 1][lr] = bv.y;
        Bs[lk + 2][lr] = bv.z; Bs[lk + 3][lr] = bv.w;
        __syncthreads();
#pragma unroll
        for (int kk = 0; kk < 16; ++kk) {
            float a[4], b[8];
            *(float4*)(a)     = *(const float4*)&As[kk][ry4];
            *(float4*)(b)     = *(const float4*)&Bs[kk][cx4];
            *(float4*)(b + 4) = *(const float4*)&Bs[kk][64 + cx4];
#pragma unroll
            for (int i = 0; i < 4; ++i)
#pragma unroll
                for (int j = 0; j < 8; ++j) acc[i][j] = fmaf(a[i], b[j], acc[i][j]);
        }
    }
#pragma unroll
    for (int i = 0; i < 4; ++i) {
        int row = bm * 128 + ry4 + i;
#pragma unroll
        for (int j = 0; j < 8; ++j) {
            int col = bn * 128 + ((j < 4) ? (cx4 + j) : (64 + cx4 + j - 4));
            Cd[(size_t)row * N + col] = acc[i][j] + bias[col];
        }
    }
}

// Same tile, split-K=2 partial variant: kz=0 -> P0, kz=1 -> P1 (no bias).
__global__ __launch_bounds__(512) void gemm_bt_128p(
    const float* __restrict__ A, const float* __restrict__ Bm,
    float* __restrict__ P0, float* __restrict__ P1,
    int M, int N, int K)
{
    __shared__ float As[16][132];
    __shared__ float Bs[16][132];
    const int bn = blockIdx.x, bm = blockIdx.y, kz = blockIdx.z;
    const int tid = threadIdx.x;
    const int lr = tid >> 2, lk = (tid & 3) * 4;
    const int cx4 = (tid & 15) * 4, ry4 = (tid >> 4) * 4;
    const int kLen = K / 2, k0b = kz * kLen;
    const float* Ap = A + (size_t)(bm * 128 + lr) * K + k0b + lk;
    const float* Bp = Bm + (size_t)(bn * 128 + lr) * K + k0b + lk;
    float acc[4][8] = {};
    for (int k0 = 0; k0 < kLen; k0 += 16) {
        float4 av = *(const float4*)(Ap + k0);
        float4 bv = *(const float4*)(Bp + k0);
        __syncthreads();
        As[lk + 0][lr] = av.x; As[lk + 1][lr] = av.y;
        As[lk + 2][lr] = av.z; As[lk + 3][lr] = av.w;
        Bs[lk + 0][lr] = bv.x; Bs[lk + 1][lr] = bv.y;
        Bs[lk + 2][lr] = bv.z; Bs[lk + 3][lr] = bv.w;
        __syncthreads();
#pragma unroll
        for (int kk = 0; kk < 16; ++kk) {
            float a[4], b[8];
            *(float4*)(a)     = *(const float4*)&As[kk][ry4];
            *(float4*)(b)     = *(const float4*)&Bs[kk][cx4];
            *(float4*)(b + 4) = *(const float4*)&Bs[kk][64 + cx4];
#pragma unroll
            for (int i = 0; i < 4; ++i)
#pragma unroll
                for (int j = 0; j < 8; ++j) acc[i][j] = fmaf(a[i], b[j], acc[i][j]);
        }
    }
    float* Cp = kz ? P1 : P0;
#pragma unroll
    for (int i = 0; i < 4; ++i) {
        int row = bm * 128 + ry4 + i;
#pragma unroll
        for (int j = 0; j < 8; ++j) {
            int col = bn * 128 + ((j < 4) ? (cx4 + j) : (64 + cx4 + j - 4));
            Cp[(size_t)row * N + col] = acc[i][j];
        }
    }
}

// C[idx] = P0[idx] + P1[idx] + bias[idx % N]   (in-place safe: C may be P0)
__global__ void reduce2_k(const float* __restrict__ P0, const float* __restrict__ P1,
                          const float* __restrict__ bias, float* __restrict__ C,
                          int MN, int N)
{
    int idx = blockIdx.x * 256 + threadIdx.x;
    if (idx >= MN) return;
    C[idx] = P0[idx] + P1[idx] + bias[idx % N];
}

// 64x64 tile GEMM helper (BK=16).
__device__ __forceinline__ void tile64(const float* __restrict__ Arow,
                                       const float* __restrict__ Brow,
                                       int K, float acc[4][4],
                                       float* __restrict__ As,
                                       float* __restrict__ Bs)
{
    const int tid = threadIdx.x;
    const int lr = tid >> 2, lc = (tid & 3) << 2;
    const int tx = tid & 15, ty = tid >> 4;
    for (int k0 = 0; k0 < K; k0 += 16) {
        float4 av = *(const float4*)(Arow + k0);
        float4 bv = *(const float4*)(Brow + k0);
        __syncthreads();
        As[lr * 17 + lc + 0] = av.x; As[lr * 17 + lc + 1] = av.y;
        As[lr * 17 + lc + 2] = av.z; As[lr * 17 + lc + 3] = av.w;
        Bs[lr * 17 + lc + 0] = bv.x; Bs[lr * 17 + lc + 1] = bv.y;
        Bs[lr * 17 + lc + 2] = bv.z; Bs[lr * 17 + lc + 3] = bv.w;
        __syncthreads();
#pragma unroll
        for (int kk = 0; kk < 16; ++kk) {
            float a[4], b[4];
#pragma unroll
            for (int i = 0; i < 4; ++i) a[i] = As[(ty * 4 + i) * 17 + kk];
#pragma unroll
            for (int j = 0; j < 4; ++j) b[j] = Bs[(tx * 4 + j) * 17 + kk];
#pragma unroll
            for (int i = 0; i < 4; ++i)
#pragma unroll
                for (int j = 0; j < 4; ++j) acc[i][j] = fmaf(a[i], b[j], acc[i][j]);
        }
    }
    __syncthreads();
}

// Split-K partials: Cpart[kz][M][N]. KS==1 -> plain GEMM to Cpart.
__global__ __launch_bounds__(256) void gemm_part(
    const float* __restrict__ A, const float* __restrict__ Bm,
    float* __restrict__ Cpart, int M, int N, int K)
{
    __shared__ float smem[2176];
    const int bn = blockIdx.x, bm = blockIdx.y, kz = blockIdx.z, KS = gridDim.z;
    const int tid = threadIdx.x;
    const int lr = tid >> 2, lc = (tid & 3) << 2;
    const int tx = tid & 15, ty = tid >> 4;
    const int kLen = K / KS, k0base = kz * kLen;
    float acc[4][4] = {};
    tile64(A + (size_t)(bm * 64 + lr) * K + k0base + lc,
           Bm + (size_t)(bn * 64 + lr) * K + k0base + lc,
           kLen, acc, smem, smem + 1088);
    float* Cp = Cpart + (size_t)kz * M * N;
#pragma unroll
    for (int i = 0; i < 4; ++i) {
        int row = bm * 64 + ty * 4 + i;
#pragma unroll
        for (int j = 0; j < 4; ++j)
            Cp[(size_t)row * N + bn * 64 + tx * 4 + j] = acc[i][j];
    }
}

__global__ void reduce_partials(const float* __restrict__ Cpart, int KS,
                                const float* __restrict__ bias,
                                const float* __restrict__ bias2,
                                float* __restrict__ C, int MN, int N)
{
    int idx = blockIdx.x * 256 + threadIdx.x;
    if (idx >= MN) return;
    float v = 0.f;
    for (int z = 0; z < KS; ++z) v += Cpart[(size_t)z * MN + idx];
    int col = idx % N;
    if (bias)  v += bias[col];
    if (bias2) v += bias2[col];
    C[idx] = v;
}

// emb_ext rows 0..63 = embed, 64 = tok_emb(SOS), 65..127 = 0; zero accums.
__global__ void init_k(const float* __restrict__ embed, const float* __restrict__ tok_emb,
                       float* __restrict__ emb_ext,
                       float* __restrict__ negent, float* __restrict__ logp)
{
    int i = blockIdx.x * 256 + threadIdx.x;
    if (i < 128 * E_) {
        int r = i >> 9, c = i & (E_ - 1);
        emb_ext[i] = (r < 64) ? embed[r * E_ + c] : ((r == 64) ? tok_emb[c] : 0.f);
    }
    if (i < B_) { negent[i] = 0.f; logp[i] = 0.f; }
}

// out_h_all[(v*64+b)][h] = LSTM(all_gates[v] + hh_gates[b]), v<66 b<64.
__global__ __launch_bounds__(256) void outh_all_k(
    const float* __restrict__ all_gates, const float* __restrict__ hh_gates,
    const float* __restrict__ enc_c0, float* __restrict__ outh)
{
    size_t idx = (size_t)blockIdx.x * 256 + threadIdx.x;
    int row = (int)(idx >> 10), h = (int)(idx & (H_ - 1));
    int v = row >> 6, b = row & 63;
    const float* ag = all_gates + (size_t)v * H4_;
    const float* hg = hh_gates + (size_t)b * H4_;
    float gi = ag[h]          + hg[h];
    float gf = ag[H_ + h]     + hg[H_ + h];
    float gg = ag[2 * H_ + h] + hg[2 * H_ + h];
    float go = ag[3 * H_ + h] + hg[3 * H_ + h];
    float cc = sigm(gf) * enc_c0[(size_t)b * H_ + h] + sigm(gi) * tanhf(gg);
    outh[idx] = sigm(go) * tanhf(cc);
}

// lg_h_all[row][v] = out_h_all[row] . out_W[v][H:2H] + out_b[v].  66 blocks.
__global__ __launch_bounds__(256) void lgh_k(
    const float* __restrict__ outh, const float* __restrict__ out_W,
    const float* __restrict__ out_b, float* __restrict__ lgh)
{
    __shared__ float smem[2176];
    const int bm = blockIdx.x;
    const int tid = threadIdx.x;
    const int lr = tid >> 2, lc = (tid & 3) << 2;
    const int tx = tid & 15, ty = tid >> 4;
    float acc[4][4] = {};
    tile64(outh + (size_t)(bm * 64 + lr) * H_ + lc,
           out_W + (size_t)lr * (2 * H_) + H_ + lc,
           H_, acc, smem, smem + 1088);
#pragma unroll
    for (int i = 0; i < 4; ++i) {
        int row = bm * 64 + ty * 4 + i;
#pragma unroll
        for (int j = 0; j < 4; ++j) {
            int col = tx * 4 + j;
            lgh[(size_t)row * V_ + col] = acc[i][j] + out_b[col];
        }
    }
}

// ---------------------------------------------------------------------------
// Scores, WIDE: 512 blocks x 4 waves; wave (b, sg) does 5 s. (validated R17)
// ---------------------------------------------------------------------------
__global__ __launch_bounds__(256) void score_k2(
    const float* __restrict__ enc_t, const float* __restrict__ dsrc,
    const float* __restrict__ attn_W, const float* __restrict__ attn_b,
    const int* __restrict__ lens, float* __restrict__ scores)
{
    const int lane = threadIdx.x & 63;
    const int gw = blockIdx.x * 4 + (threadIdx.x >> 6);
    const int b = gw >> 5, sg = gw & 31;
    float dec_r[16], aw_r[16];
    const float* dr = dsrc + (size_t)b * H_;
#pragma unroll
    for (int it = 0; it < 16; ++it) {
        int h = lane + it * 64;
        dec_r[it] = dr[h];
        aw_r[it] = attn_W[h];
    }
    const int len = lens[b];
    const float ab = attn_b[0];
    for (int s = sg * 5; s < sg * 5 + 5; ++s) {
        if (s >= len) { if (lane == 0) scores[b * S_ + s] = -1e9f; continue; }
        const float* ep = enc_t + ((size_t)s * B_ + b) * H_;
        float acc = 0.f;
#pragma unroll
        for (int it = 0; it < 16; ++it)
            acc += aw_r[it] * tanhf(ep[lane + it * 64] + dec_r[it]);
        for (int d = 32; d; d >>= 1) acc += __shfl_xor(acc, d);
        if (lane == 0) scores[b * S_ + s] = acc + ab;
    }
}

// ---------------------------------------------------------------------------
// Tail: softmax + attn-out + context + ctx-half logits (+ precomputed lg-half)
// + renorm/argmax/stats + value-gather next dec_sel/lg_sel. (validated R17)
// ---------------------------------------------------------------------------
__global__ __launch_bounds__(256) void smax_out2_k(
    const float* __restrict__ scores, const float* __restrict__ enc_out,
    const float* __restrict__ out_W, const float* __restrict__ lsrc,
    const int* __restrict__ lens,
    const float* __restrict__ dec_all, const float* __restrict__ lg_h_all,
    float* __restrict__ dec_sel, float* __restrict__ lg_sel,
    float* __restrict__ negent_acc, float* __restrict__ logp_acc,
    float* __restrict__ out, int t)
{
    __shared__ float sc[S_];
    __shared__ float comb[H_];
    __shared__ float lg[V_];
    __shared__ int tok_s;
    const int tid = threadIdx.x;
    const int b = blockIdx.x;
    const int lane = tid & 63, wv = tid >> 6;
    if (wv == 0) {
        float m = -1e30f;
        for (int s = lane; s < S_; s += 64) {
            float v = scores[b * S_ + s]; sc[s] = v; m = fmaxf(m, v);
        }
        for (int d = 32; d; d >>= 1) m = fmaxf(m, __shfl_xor(m, d));
        float sum = 0.f;
        for (int s = lane; s < S_; s += 64) {
            float e = expf(sc[s] - m); sc[s] = e; sum += e;
        }
        for (int d = 32; d; d >>= 1) sum += __shfl_xor(sum, d);
        float inv = 1.f / sum;
        for (int s = lane; s < S_; s += 64) {
            float pr = sc[s] * inv; sc[s] = pr;
            out[T_ * B_ + ((size_t)b * T_ + t) * S_ + s] = pr;
        }
    }
    __syncthreads();
    {
        const int len4 = (lens[b] + 3) & ~3;
        const float* base = enc_out + (size_t)b * H_ + tid * 4;
        float4 ac0 = {0,0,0,0}, ac1 = {0,0,0,0}, ac2 = {0,0,0,0}, ac3 = {0,0,0,0};
        for (int s = 0; s < len4; s += 4) {
            float4 e0 = *(const float4*)(base + (size_t)(s    ) * B_ * H_);
            float4 e1 = *(const float4*)(base + (size_t)(s + 1) * B_ * H_);
            float4 e2 = *(const float4*)(base + (size_t)(s + 2) * B_ * H_);
            float4 e3 = *(const float4*)(base + (size_t)(s + 3) * B_ * H_);
            float p0 = sc[s], p1 = sc[s + 1], p2 = sc[s + 2], p3 = sc[s + 3];
            ac0.x = fmaf(p0, e0.x, ac0.x); ac0.y = fmaf(p0, e0.y, ac0.y);
            ac0.z = fmaf(p0, e0.z, ac0.z); ac0.w = fmaf(p0, e0.w, ac0.w);
            ac1.x = fmaf(p1, e1.x, ac1.x); ac1.y = fmaf(p1, e1.y, ac1.y);
            ac1.z = fmaf(p1, e1.z, ac1.z); ac1.w = fmaf(p1, e1.w, ac1.w);
            ac2.x = fmaf(p2, e2.x, ac2.x); ac2.y = fmaf(p2, e2.y, ac2.y);
            ac2.z = fmaf(p2, e2.z, ac2.z); ac2.w = fmaf(p2, e2.w, ac2.w);
            ac3.x = fmaf(p3, e3.x, ac3.x); ac3.y = fmaf(p3, e3.y, ac3.y);
            ac3.z = fmaf(p3, e3.z, ac3.z); ac3.w = fmaf(p3, e3.w, ac3.w);
        }
        comb[tid * 4 + 0] = ac0.x + ac1.x + ac2.x + ac3.x;
        comb[tid * 4 + 1] = ac0.y + ac1.y + ac2.y + ac3.y;
        comb[tid * 4 + 2] = ac0.z + ac1.z + ac2.z + ac3.z;
        comb[tid * 4 + 3] = ac0.w + ac1.w + ac2.w + ac3.w;
    }
    __syncthreads();
    for (int v = wv * 16; v < wv * 16 + 16; ++v) {
        const float* w = out_W + (size_t)v * (2 * H_);
        float a0 = 0.f, a1 = 0.f;
#pragma unroll
        for (int j = 0; j < 16; j += 2) {
            a0 = fmaf(comb[lane + j * 64], w[lane + j * 64], a0);
            a1 = fmaf(comb[lane + (j + 1) * 64], w[lane + (j + 1) * 64], a1);
        }
        float acc = a0 + a1;
        for (int d = 32; d; d >>= 1) acc += __shfl_xor(acc, d);
        if (lane == 0) lg[v] = acc + lsrc[(size_t)b * V_ + v];
    }
    __syncthreads();
    if (wv == 0) {
        float x = lg[lane];
        float m = x;
        for (int d = 32; d; d >>= 1) m = fmaxf(m, __shfl_xor(m, d));
        float e = expf(x - m);
        float s = e;
        for (int d = 32; d; d >>= 1) s += __shfl_xor(s, d);
        float pr = e / s;
        float ps = pr;
        for (int d = 32; d; d >>= 1) ps += __shfl_xor(ps, d);
        pr = pr / ps;   // reference renormalizes
        float bv = pr; int bi = lane;
        for (int d = 32; d; d >>= 1) {
            float ov = __shfl_xor(bv, d); int oi = __shfl_xor(bi, d);
            if (ov > bv || (ov == bv && oi < bi)) { bv = ov; bi = oi; }
        }
        float ne = pr * logf(pr + 1e-6f);
        for (int d = 32; d; d >>= 1) ne += __shfl_xor(ne, d);
        float ptok = __shfl(pr, bi);
        if (lane == 0) {
            out[t * B_ + b] = (float)bi;
            float na = negent_acc[b] + ne;                negent_acc[b] = na;
            float la = logp_acc[b] + logf(ptok + 1e-6f);  logp_acc[b] = la;
            if (t == T_ - 1) {
                out[T_ * B_ + B_ * T_ * S_ + b] = na;
                out[T_ * B_ + B_ * T_ * S_ + B_ + b] = la;
            }
            tok_s = bi;
        }
    }
    __syncthreads();
    {
        const int tk = tok_s;
        const float4* src = (const float4*)(dec_all + (size_t)(tk * 64 + b) * H_);
        float4* dst = (float4*)(dec_sel + (size_t)b * H_);
        dst[tid] = src[tid];
        if (tid < V_)
            lg_sel[(size_t)b * V_ + tid] = lg_h_all[(size_t)(tk * 64 + b) * V_ + tid];
    }
}

// ------------------- fallback path kernels (validated R15) -----------------
__global__ __launch_bounds__(256) void lstm_gather_k(
    const float* __restrict__ gsrc, size_t strideB,
    const float* __restrict__ hh_gates, const float* __restrict__ enc_c0,
    float* __restrict__ out_h)
{
    int idx = blockIdx.x * 256 + threadIdx.x;
    int b = idx >> 10, h = idx & (H_ - 1);
    const float* ag = gsrc + (size_t)b * strideB;
    const float* hg = hh_gates + (size_t)b * H4_;
    float gi = ag[h]           + hg[h];
    float gf = ag[H_ + h]      + hg[H_ + h];
    float gg = ag[2 * H_ + h]  + hg[2 * H_ + h];
    float go = ag[3 * H_ + h]  + hg[3 * H_ + h];
    float cc = sigm(gf) * enc_c0[idx] + sigm(gi) * tanhf(gg);
    out_h[idx] = sigm(go) * tanhf(cc);
}

__global__ __launch_bounds__(256) void score_k(
    const float* __restrict__ enc_t, const float* __restrict__ dec_part,
    const float* __restrict__ dec_b, const float* __restrict__ attn_W,
    const float* __restrict__ attn_b, const int* __restrict__ lens,
    float* __restrict__ scores)
{
    const int lane = threadIdx.x & 63;
    const int gw = blockIdx.x * 4 + (threadIdx.x >> 6);
    const int b = gw >> 5, sg = gw & 31;
    float dec_r[16], aw_r[16];
#pragma unroll
    for (int it = 0; it < 16; ++it) {
        int h = lane + it * 64;
        dec_r[it] = dec_part[(size_t)b * H_ + h]
                  + dec_part[(size_t)(B_ + b) * H_ + h]
                  + dec_part[(size_t)(2 * B_ + b) * H_ + h]
                  + dec_part[(size_t)(3 * B_ + b) * H_ + h]
                  + dec_b[h];
        aw_r[it] = attn_W[h];
    }
    const int len = lens[b];
    const float ab = attn_b[0];
    for (int s = sg * 5; s < sg * 5 + 5; ++s) {
        if (s >= len) { if (lane == 0) scores[b * S_ + s] = -1e9f; continue; }
        const float* ep = enc_t + ((size_t)s * B_ + b) * H_;
        float acc = 0.f;
#pragma unroll
        for (int it = 0; it < 16; ++it)
            acc += aw_r[it] * tanhf(ep[lane + it * 64] + dec_r[it]);
        for (int d = 32; d; d >>= 1) acc += __shfl_xor(acc, d);
        if (lane == 0) scores[b * S_ + s] = acc + ab;
    }
}

__global__ __launch_bounds__(256) void smax_out_k(
    const float* __restrict__ scores, const float* __restrict__ enc_out,
    const float* __restrict__ out_h, const float* __restrict__ out_W,
    const float* __restrict__ out_b, const float* __restrict__ all_gates,
    const int* __restrict__ lens, float* __restrict__ gates_sel,
    float* __restrict__ negent_acc, float* __restrict__ logp_acc,
    float* __restrict__ out, int t)
{
    __shared__ float sc[S_];
    __shared__ float comb[2 * H_];
    __shared__ float lg[V_];
    __shared__ int tok_s;
    const int tid = threadIdx.x;
    const int b = blockIdx.x;
    const int lane = tid & 63, wv = tid >> 6;
    if (wv == 0) {
        float m = -1e30f;
        for (int s = lane; s < S_; s += 64) {
            float v = scores[b * S_ + s]; sc[s] = v; m = fmaxf(m, v);
        }
        for (int d = 32; d; d >>= 1) m = fmaxf(m, __shfl_xor(m, d));
        float sum = 0.f;
        for (int s = lane; s < S_; s += 64) {
            float e = expf(sc[s] - m); sc[s] = e; sum += e;
        }
        for (int d = 32; d; d >>= 1) sum += __shfl_xor(sum, d);
        float inv = 1.f / sum;
        for (int s = lane; s < S_; s += 64) {
            float pr = sc[s] * inv; sc[s] = pr;
            out[T_ * B_ + ((size_t)b * T_ + t) * S_ + s] = pr;
        }
    }
    __syncthreads();
    {
        const int len4 = (lens[b] + 3) & ~3;
        const float* base = enc_out + (size_t)b * H_ + tid * 4;
        float4 ac0 = {0,0,0,0}, ac1 = {0,0,0,0}, ac2 = {0,0,0,0}, ac3 = {0,0,0,0};
        for (int s = 0; s < len4; s += 4) {
            float4 e0 = *(const float4*)(base + (size_t)(s    ) * B_ * H_);
            float4 e1 = *(const float4*)(base + (size_t)(s + 1) * B_ * H_);
            float4 e2 = *(const float4*)(base + (size_t)(s + 2) * B_ * H_);
            float4 e3 = *(const float4*)(base + (size_t)(s + 3) * B_ * H_);
            float p0 = sc[s], p1 = sc[s + 1], p2 = sc[s + 2], p3 = sc[s + 3];
            ac0.x = fmaf(p0, e0.x, ac0.x); ac0.y = fmaf(p0, e0.y, ac0.y);
            ac0.z = fmaf(p0, e0.z, ac0.z); ac0.w = fmaf(p0, e0.w, ac0.w);
            ac1.x = fmaf(p1, e1.x, ac1.x); ac1.y = fmaf(p1, e1.y, ac1.y);
            ac1.z = fmaf(p1, e1.z, ac1.z); ac1.w = fmaf(p1, e1.w, ac1.w);
            ac2.x = fmaf(p2, e2.x, ac2.x); ac2.y = fmaf(p2, e2.y, ac2.y);
            ac2.z = fmaf(p2, e2.z, ac2.z); ac2.w = fmaf(p2, e2.w, ac2.w);
            ac3.x = fmaf(p3, e3.x, ac3.x); ac3.y = fmaf(p3, e3.y, ac3.y);
            ac3.z = fmaf(p3, e3.z, ac3.z); ac3.w = fmaf(p3, e3.w, ac3.w);
        }
        comb[tid * 4 + 0] = ac0.x + ac1.x + ac2.x + ac3.x;
        comb[tid * 4 + 1] = ac0.y + ac1.y + ac2.y + ac3.y;
        comb[tid * 4 + 2] = ac0.z + ac1.z + ac2.z + ac3.z;
        comb[tid * 4 + 3] = ac0.w + ac1.w + ac2.w + ac3.w;
    }
    for (int i = tid; i < H_; i += 256) comb[H_ + i] = out_h[(size_t)b * H_ + i];
    __syncthreads();
    for (int v = wv * 16; v < wv * 16 + 16; ++v) {
        const float* w = out_W + (size_t)v * (2 * H_);
        float a0 = 0.f, a1 = 0.f;
#pragma unroll
        for (int j = 0; j < 32; j += 2) {
            a0 = fmaf(comb[lane + j * 64], w[lane + j * 64], a0);
            a1 = fmaf(comb[lane + (j + 1) * 64], w[lane + (j + 1) * 64], a1);
        }
        float acc = a0 + a1;
        for (int d = 32; d; d >>= 1) acc += __shfl_xor(acc, d);
        if (lane == 0) lg[v] = acc + out_b[v];
    }
    __syncthreads();
    if (wv == 0) {
        float x = lg[lane];
        float m = x;
        for (int d = 32; d; d >>= 1) m = fmaxf(m, __shfl_xor(m, d));
        float e = expf(x - m);
        float s = e;
        for (int d = 32; d; d >>= 1) s += __shfl_xor(s, d);
        float pr = e / s;
        float ps = pr;
        for (int d = 32; d; d >>= 1) ps += __shfl_xor(ps, d);
        pr = pr / ps;
        float bv = pr; int bi = lane;
        for (int d = 32; d; d >>= 1) {
            float ov = __shfl_xor(bv, d); int oi = __shfl_xor(bi, d);
            if (ov > bv || (ov == bv && oi < bi)) { bv = ov; bi = oi; }
        }
        float ne = pr * logf(pr + 1e-6f);
        for (int d = 32; d; d >>= 1) ne += __shfl_xor(ne, d);
        float ptok = __shfl(pr, bi);
        if (lane == 0) {
            out[t * B_ + b] = (float)bi;
            float na = negent_acc[b] + ne;                negent_acc[b] = na;
            float la = logp_acc[b] + logf(ptok + 1e-6f);  logp_acc[b] = la;
            if (t == T_ - 1) {
                out[T_ * B_ + B_ * T_ * S_ + b] = na;
                out[T_ * B_ + B_ * T_ * S_ + B_ + b] = la;
            }
            tok_s = bi;
        }
    }
    __syncthreads();
    {
        const int tk = tok_s;
        const float4* src = (const float4*)(all_gates + (size_t)tk * H4_);
        float4* dst = (float4*)(gates_sel + (size_t)b * H4_);
        for (int i = tid; i < H4_ / 4; i += 256) dst[i] = src[i];
    }
}

extern "C" void kernel_launch(void* const* d_in, const int* in_sizes, int n_in,
                              void* d_out, int out_size, void* d_ws, size_t ws_size,
                              hipStream_t stream) {
    const float* enc_h0  = (const float*)d_in[0];
    const float* enc_c0  = (const float*)d_in[1];
    const float* enc_out = (const float*)d_in[2];
    const int*   lens    = (const int*)d_in[3];
    const float* tok_emb = (const float*)d_in[4];
    const float* embed   = (const float*)d_in[5];
    const float* W_ih    = (const float*)d_in[6];
    const float* W_hh    = (const float*)d_in[7];
    const float* b_ih    = (const float*)d_in[8];
    const float* b_hh    = (const float*)d_in[9];
    const float* out_W   = (const float*)d_in[10];
    const float* out_b   = (const float*)d_in[11];
    const float* enc_W   = (const float*)d_in[12];
    const float* enc_b   = (const float*)d_in[13];
    const float* dec_W   = (const float*)d_in[14];
    const float* dec_b   = (const float*)d_in[15];
    const float* attn_W  = (const float*)d_in[16];
    const float* attn_b  = (const float*)d_in[17];
    float* out = (float*)d_out;

    float* ws = (float*)d_ws;

    if (ws_size >= 64012800u) {
        // -------- fast path: dec/lg precompute, 2 launches per step --------
        float* hh_gates  = ws;                          // 262144
        float* dec_sel   = hh_gates + B_ * H4_;         // 65536
        float* lg_sel    = dec_sel + B_ * H_;           // 4096
        float* negent    = lg_sel + B_ * V_;            // 64
        float* logp      = negent + B_;                 // 64
        float* emb_ext   = logp + B_;                   // 65536
        float* all_gates = emb_ext + 128 * E_;          // 524288
        float* lg_h_all  = all_gates + (size_t)128 * H4_;   // 270336
        float* dec_all   = lg_h_all + (size_t)66 * 64 * V_; // 4325376
        float* enc_t     = dec_all + (size_t)66 * 64 * H_;  // 10485760
        float* outh_tmp  = enc_t;        // alias: 4,325,376 (dead before enc_t GEMM)
        float* part      = enc_t;        // alias: 1,048,576 (dead before outh)
        float* dec_p1    = enc_t + (size_t)66 * 64 * H_;    // alias: spare tail?
        // dec split-K partial kz=1 goes in enc_t region AFTER outh_tmp:
        dec_p1 = enc_t + (size_t)66 * 64 * H_ - 0;  // recompute below properly
        dec_p1 = enc_t + 4325376;        // 4,325,376..8,650,752 of enc_t region
        float* scores    = emb_ext;      // emb_ext dead after all_gates GEMM

        init_k<<<(128 * E_ + 255) / 256, 256, 0, stream>>>(embed, tok_emb, emb_ext,
                                                           negent, logp);
        gemm_part<<<dim3(H4_ / 64, 1, 4), 256, 0, stream>>>(enc_h0, W_hh, part, B_, H4_, H_);
        reduce_partials<<<(B_ * H4_ + 255) / 256, 256, 0, stream>>>(
            part, 4, b_ih, b_hh, hh_gates, B_ * H4_, H4_);
        gemm_part<<<dim3(H4_ / 64, 2, 1), 256, 0, stream>>>(emb_ext, W_ih, all_gates,
                                                            128, H4_, E_);
        outh_all_k<<<(66 * 64 * H_) / 256, 256, 0, stream>>>(all_gates, hh_gates,
                                                             enc_c0, outh_tmp);
        // dec_all = outh_tmp @ dec_W^T + dec_b, split-K=2 (528 blocks)
        gemm_bt_128p<<<dim3(H_ / 128, (66 * 64) / 128, 2), 512, 0, stream>>>(
            outh_tmp, dec_W, dec_all, dec_p1, 66 * 64, H_, H_);
        reduce2_k<<<(66 * 64 * H_ + 255) / 256, 256, 0, stream>>>(
            dec_all, dec_p1, dec_b, dec_all, 66 * 64 * H_, H_);
        lgh_k<<<66, 256, 0, stream>>>(outh_tmp, out_W, out_b, lg_h_all);
        gemm_bt_128<<<dim3(H_ / 128, (S_ * B_) / 128), 512, 0, stream>>>(
            enc_out, enc_W, enc_b, enc_t, S_ * B_, H_, H_);

        for (int t = 0; t < T_; ++t) {
            const float* dsrc = (t == 0) ? (dec_all + (size_t)(64 * 64) * H_) : dec_sel;
            const float* lsrc = (t == 0) ? (lg_h_all + (size_t)(64 * 64) * V_) : lg_sel;
            score_k2<<<512, 256, 0, stream>>>(enc_t, dsrc, attn_W, attn_b, lens, scores);
            smax_out2_k<<<B_, 256, 0, stream>>>(scores, enc_out, out_W, lsrc, lens,
                                                dec_all, lg_h_all, dec_sel, lg_sel,
                                                negent, logp, out, t);
        }
        return;
    }

    // ---------------- fallback path: validated round 15 ---------------------
    float* hh_gates  = ws;                         // 262144
    float* out_h     = hh_gates + B_ * H4_;        // 65536
    float* dec_part  = out_h + B_ * H_;            // 262144
    float* scores    = dec_part + 4 * B_ * H_;     // 10240
    float* negent    = scores + B_ * S_;           // 64
    float* logp      = negent + B_;                // 64
    float* gates_sel = logp + B_;                  // 262144
    float* emb_ext   = gates_sel + B_ * H4_;       // 65536
    float* all_gates = emb_ext + 128 * E_;         // 524288
    float* enc_t     = all_gates + (size_t)128 * H4_;  // 10485760
    float* part      = enc_t;
    if (ws_size < 47751680u) return;

    init_k<<<(128 * E_ + 255) / 256, 256, 0, stream>>>(embed, tok_emb, emb_ext,
                                                       negent, logp);
    gemm_part<<<dim3(H4_ / 64, 1, 4), 256, 0, stream>>>(enc_h0, W_hh, part, B_, H4_, H_);
    reduce_partials<<<(B_ * H4_ + 255) / 256, 256, 0, stream>>>(
        part, 4, b_ih, b_hh, hh_gates, B_ * H4_, H4_);
    gemm_part<<<dim3(H4_ / 64, 2, 1), 256, 0, stream>>>(emb_ext, W_ih, all_gates,
                                                        128, H4_, E_);
    gemm_bt_128<<<dim3(H_ / 128, (S_ * B_) / 128), 512, 0, stream>>>(
        enc_out, enc_W, enc_b, enc_t, S_ * B_, H_, H_);

    for (int t = 0; t < T_; ++t) {
        const float* gsrc = (t == 0) ? (all_gates + (size_t)64 * H4_) : gates_sel;
        const size_t strideB = (t == 0) ? 0 : (size_t)H4_;
        lstm_gather_k<<<(B_ * H_) / 256, 256, 0, stream>>>(gsrc, strideB, hh_gates,
                                                           enc_c0, out_h);
        gemm_part<<<dim3(H_ / 64, 1, 4), 256, 0, stream>>>(out_h, dec_W, dec_part, B_, H_, H_);
        score_k<<<512, 256, 0, stream>>>(enc_t, dec_part, dec_b, attn_W, attn_b, lens, scores);
        smax_out_k<<<64, 256, 0, stream>>>(scores, enc_out, out_h, out_W, out_b,
                                           all_gates, lens, gates_sel, negent, logp, out, t);
    }
}

// Round 19
// 1454.181 us; speedup vs baseline: 2.0164x; 1.0305x over previous
//
#include <hip/hip_runtime.h>

#define S_ 160
#define B_ 64
#define H_ 1024
#define E_ 512
#define V_ 64
#define T_ 16
#define H4_ 4096

__device__ __forceinline__ float sigm(float x) { return 1.f / (1.f + expf(-x)); }

// ---------------------------------------------------------------------------
// C = A @ Bm^T + bias. 128x128 tile, BK=16, 512 threads, 4x8 acc/thread.
// (validated rounds 15-18)
// ---------------------------------------------------------------------------
__global__ __launch_bounds__(512) void gemm_bt_128(
    const float* __restrict__ A, const float* __restrict__ Bm,
    const float* __restrict__ bias, float* __restrict__ Cd,
    int M, int N, int K)
{
    __shared__ float As[16][132];
    __shared__ float Bs[16][132];
    const int bn = blockIdx.x, bm = blockIdx.y;
    const int tid = threadIdx.x;
    const int lr = tid >> 2, lk = (tid & 3) * 4;
    const int cx4 = (tid & 15) * 4, ry4 = (tid >> 4) * 4;
    const float* Ap = A + (size_t)(bm * 128 + lr) * K + lk;
    const float* Bp = Bm + (size_t)(bn * 128 + lr) * K + lk;
    float acc[4][8] = {};
    for (int k0 = 0; k0 < K; k0 += 16) {
        float4 av = *(const float4*)(Ap + k0);
        float4 bv = *(const float4*)(Bp + k0);
        __syncthreads();
        As[lk + 0][lr] = av.x; As[lk + 1][lr] = av.y;
        As[lk + 2][lr] = av.z; As[lk + 3][lr] = av.w;
        Bs[lk + 0][lr] = bv.x; Bs[lk + 1][lr] = bv.y;
        Bs[lk + 2][lr] = bv.z; Bs[lk + 3][lr] = bv.w;
        __syncthreads();
#pragma unroll
        for (int kk = 0; kk < 16; ++kk) {
            float a[4], b[8];
            *(float4*)(a)     = *(const float4*)&As[kk][ry4];
            *(float4*)(b)     = *(const float4*)&Bs[kk][cx4];
            *(float4*)(b + 4) = *(const float4*)&Bs[kk][64 + cx4];
#pragma unroll
            for (int i = 0; i < 4; ++i)
#pragma unroll
                for (int j = 0; j < 8; ++j) acc[i][j] = fmaf(a[i], b[j], acc[i][j]);
        }
    }
#pragma unroll
    for (int i = 0; i < 4; ++i) {
        int row = bm * 128 + ry4 + i;
#pragma unroll
        for (int j = 0; j < 8; ++j) {
            int col = bn * 128 + ((j < 4) ? (cx4 + j) : (64 + cx4 + j - 4));
            Cd[(size_t)row * N + col] = acc[i][j] + bias[col];
        }
    }
}

// Same tile, split-K=2 partial variant: kz=0 -> P0, kz=1 -> P1 (no bias).
__global__ __launch_bounds__(512) void gemm_bt_128p(
    const float* __restrict__ A, const float* __restrict__ Bm,
    float* __restrict__ P0, float* __restrict__ P1,
    int M, int N, int K)
{
    __shared__ float As[16][132];
    __shared__ float Bs[16][132];
    const int bn = blockIdx.x, bm = blockIdx.y, kz = blockIdx.z;
    const int tid = threadIdx.x;
    const int lr = tid >> 2, lk = (tid & 3) * 4;
    const int cx4 = (tid & 15) * 4, ry4 = (tid >> 4) * 4;
    const int kLen = K / 2, k0b = kz * kLen;
    const float* Ap = A + (size_t)(bm * 128 + lr) * K + k0b + lk;
    const float* Bp = Bm + (size_t)(bn * 128 + lr) * K + k0b + lk;
    float acc[4][8] = {};
    for (int k0 = 0; k0 < kLen; k0 += 16) {
        float4 av = *(const float4*)(Ap + k0);
        float4 bv = *(const float4*)(Bp + k0);
        __syncthreads();
        As[lk + 0][lr] = av.x; As[lk + 1][lr] = av.y;
        As[lk + 2][lr] = av.z; As[lk + 3][lr] = av.w;
        Bs[lk + 0][lr] = bv.x; Bs[lk + 1][lr] = bv.y;
        Bs[lk + 2][lr] = bv.z; Bs[lk + 3][lr] = bv.w;
        __syncthreads();
#pragma unroll
        for (int kk = 0; kk < 16; ++kk) {
            float a[4], b[8];
            *(float4*)(a)     = *(const float4*)&As[kk][ry4];
            *(float4*)(b)     = *(const float4*)&Bs[kk][cx4];
            *(float4*)(b + 4) = *(const float4*)&Bs[kk][64 + cx4];
#pragma unroll
            for (int i = 0; i < 4; ++i)
#pragma unroll
                for (int j = 0; j < 8; ++j) acc[i][j] = fmaf(a[i], b[j], acc[i][j]);
        }
    }
    float* Cp = kz ? P1 : P0;
#pragma unroll
    for (int i = 0; i < 4; ++i) {
        int row = bm * 128 + ry4 + i;
#pragma unroll
        for (int j = 0; j < 8; ++j) {
            int col = bn * 128 + ((j < 4) ? (cx4 + j) : (64 + cx4 + j - 4));
            Cp[(size_t)row * N + col] = acc[i][j];
        }
    }
}

// C[idx] = P0[idx] + P1[idx] + bias[idx % N]   (in-place safe: C may be P0)
__global__ void reduce2_k(const float* __restrict__ P0, const float* __restrict__ P1,
                          const float* __restrict__ bias, float* __restrict__ C,
                          int MN, int N)
{
    int idx = blockIdx.x * 256 + threadIdx.x;
    if (idx >= MN) return;
    C[idx] = P0[idx] + P1[idx] + bias[idx % N];
}

// 64x64 tile GEMM helper (BK=16).
__device__ __forceinline__ void tile64(const float* __restrict__ Arow,
                                       const float* __restrict__ Brow,
                                       int K, float acc[4][4],
                                       float* __restrict__ As,
                                       float* __restrict__ Bs)
{
    const int tid = threadIdx.x;
    const int lr = tid >> 2, lc = (tid & 3) << 2;
    const int tx = tid & 15, ty = tid >> 4;
    for (int k0 = 0; k0 < K; k0 += 16) {
        float4 av = *(const float4*)(Arow + k0);
        float4 bv = *(const float4*)(Brow + k0);
        __syncthreads();
        As[lr * 17 + lc + 0] = av.x; As[lr * 17 + lc + 1] = av.y;
        As[lr * 17 + lc + 2] = av.z; As[lr * 17 + lc + 3] = av.w;
        Bs[lr * 17 + lc + 0] = bv.x; Bs[lr * 17 + lc + 1] = bv.y;
        Bs[lr * 17 + lc + 2] = bv.z; Bs[lr * 17 + lc + 3] = bv.w;
        __syncthreads();
#pragma unroll
        for (int kk = 0; kk < 16; ++kk) {
            float a[4], b[4];
#pragma unroll
            for (int i = 0; i < 4; ++i) a[i] = As[(ty * 4 + i) * 17 + kk];
#pragma unroll
            for (int j = 0; j < 4; ++j) b[j] = Bs[(tx * 4 + j) * 17 + kk];
#pragma unroll
            for (int i = 0; i < 4; ++i)
#pragma unroll
                for (int j = 0; j < 4; ++j) acc[i][j] = fmaf(a[i], b[j], acc[i][j]);
        }
    }
    __syncthreads();
}

// Split-K partials: Cpart[kz][M][N]. KS==1 -> plain GEMM to Cpart.
__global__ __launch_bounds__(256) void gemm_part(
    const float* __restrict__ A, const float* __restrict__ Bm,
    float* __restrict__ Cpart, int M, int N, int K)
{
    __shared__ float smem[2176];
    const int bn = blockIdx.x, bm = blockIdx.y, kz = blockIdx.z, KS = gridDim.z;
    const int tid = threadIdx.x;
    const int lr = tid >> 2, lc = (tid & 3) << 2;
    const int tx = tid & 15, ty = tid >> 4;
    const int kLen = K / KS, k0base = kz * kLen;
    float acc[4][4] = {};
    tile64(A + (size_t)(bm * 64 + lr) * K + k0base + lc,
           Bm + (size_t)(bn * 64 + lr) * K + k0base + lc,
           kLen, acc, smem, smem + 1088);
    float* Cp = Cpart + (size_t)kz * M * N;
#pragma unroll
    for (int i = 0; i < 4; ++i) {
        int row = bm * 64 + ty * 4 + i;
#pragma unroll
        for (int j = 0; j < 4; ++j)
            Cp[(size_t)row * N + bn * 64 + tx * 4 + j] = acc[i][j];
    }
}

__global__ void reduce_partials(const float* __restrict__ Cpart, int KS,
                                const float* __restrict__ bias,
                                const float* __restrict__ bias2,
                                float* __restrict__ C, int MN, int N)
{
    int idx = blockIdx.x * 256 + threadIdx.x;
    if (idx >= MN) return;
    float v = 0.f;
    for (int z = 0; z < KS; ++z) v += Cpart[(size_t)z * MN + idx];
    int col = idx % N;
    if (bias)  v += bias[col];
    if (bias2) v += bias2[col];
    C[idx] = v;
}

// emb_ext rows 0..63 = embed, 64 = tok_emb(SOS), 65..127 = 0; zero accums.
__global__ void init_k(const float* __restrict__ embed, const float* __restrict__ tok_emb,
                       float* __restrict__ emb_ext,
                       float* __restrict__ negent, float* __restrict__ logp)
{
    int i = blockIdx.x * 256 + threadIdx.x;
    if (i < 128 * E_) {
        int r = i >> 9, c = i & (E_ - 1);
        emb_ext[i] = (r < 64) ? embed[r * E_ + c] : ((r == 64) ? tok_emb[c] : 0.f);
    }
    if (i < B_) { negent[i] = 0.f; logp[i] = 0.f; }
}

// ---------------------------------------------------------------------------
// out_h_all[(v*64+b)][h] = LSTM(all_gates[v] + sum4(hh_part) + b_ih + b_hh).
// Sums the hh split-K partials inline (L2-resident across the 66x v-reuse),
// removing the reduce_partials launch from the critical setup chain.
// ---------------------------------------------------------------------------
__global__ __launch_bounds__(256) void outh_all_k(
    const float* __restrict__ all_gates, const float* __restrict__ hh_part,
    const float* __restrict__ b_ih, const float* __restrict__ b_hh,
    const float* __restrict__ enc_c0, float* __restrict__ outh)
{
    size_t idx = (size_t)blockIdx.x * 256 + threadIdx.x;
    int row = (int)(idx >> 10), h = (int)(idx & (H_ - 1));
    int v = row >> 6, b = row & 63;
    const float* ag = all_gates + (size_t)v * H4_;
    const size_t hb = (size_t)b * H4_;
    const size_t P = (size_t)B_ * H4_;
    float g4[4];
#pragma unroll
    for (int g = 0; g < 4; ++g) {
        size_t c = hb + g * H_ + h;
        g4[g] = ag[g * H_ + h]
              + hh_part[c] + hh_part[P + c] + hh_part[2 * P + c] + hh_part[3 * P + c]
              + b_ih[g * H_ + h] + b_hh[g * H_ + h];
    }
    float cc = sigm(g4[1]) * enc_c0[(size_t)b * H_ + h] + sigm(g4[0]) * tanhf(g4[2]);
    outh[idx] = sigm(g4[3]) * tanhf(cc);
}

// lg_h_all[row][v] = out_h_all[row] . out_W[v][H:2H] + out_b[v].  66 blocks.
__global__ __launch_bounds__(256) void lgh_k(
    const float* __restrict__ outh, const float* __restrict__ out_W,
    const float* __restrict__ out_b, float* __restrict__ lgh)
{
    __shared__ float smem[2176];
    const int bm = blockIdx.x;
    const int tid = threadIdx.x;
    const int lr = tid >> 2, lc = (tid & 3) << 2;
    const int tx = tid & 15, ty = tid >> 4;
    float acc[4][4] = {};
    tile64(outh + (size_t)(bm * 64 + lr) * H_ + lc,
           out_W + (size_t)lr * (2 * H_) + H_ + lc,
           H_, acc, smem, smem + 1088);
#pragma unroll
    for (int i = 0; i < 4; ++i) {
        int row = bm * 64 + ty * 4 + i;
#pragma unroll
        for (int j = 0; j < 4; ++j) {
            int col = tx * 4 + j;
            lgh[(size_t)row * V_ + col] = acc[i][j] + out_b[col];
        }
    }
}

// ---------------------------------------------------------------------------
// Scores, WIDE: 512 blocks x 4 waves; wave (b, sg) does 5 s. (validated R17/18)
// ---------------------------------------------------------------------------
__global__ __launch_bounds__(256) void score_k2(
    const float* __restrict__ enc_t, const float* __restrict__ dsrc,
    const float* __restrict__ attn_W, const float* __restrict__ attn_b,
    const int* __restrict__ lens, float* __restrict__ scores)
{
    const int lane = threadIdx.x & 63;
    const int gw = blockIdx.x * 4 + (threadIdx.x >> 6);
    const int b = gw >> 5, sg = gw & 31;
    float dec_r[16], aw_r[16];
    const float* dr = dsrc + (size_t)b * H_;
#pragma unroll
    for (int it = 0; it < 16; ++it) {
        int h = lane + it * 64;
        dec_r[it] = dr[h];
        aw_r[it] = attn_W[h];
    }
    const int len = lens[b];
    const float ab = attn_b[0];
    for (int s = sg * 5; s < sg * 5 + 5; ++s) {
        if (s >= len) { if (lane == 0) scores[b * S_ + s] = -1e9f; continue; }
        const float* ep = enc_t + ((size_t)s * B_ + b) * H_;
        float acc = 0.f;
#pragma unroll
        for (int it = 0; it < 16; ++it)
            acc += aw_r[it] * tanhf(ep[lane + it * 64] + dec_r[it]);
        for (int d = 32; d; d >>= 1) acc += __shfl_xor(acc, d);
        if (lane == 0) scores[b * S_ + s] = acc + ab;
    }
}

// ---------------------------------------------------------------------------
// Tail, 512 threads (8 waves): softmax + attn-out + context (2h/thr float2)
// + ctx-half logits (8 waves x 8 v) + renorm/argmax/stats + value-gather.
// One block per b. (phases validated in R16 step_k / R17-18 smax_out2)
// ---------------------------------------------------------------------------
__global__ __launch_bounds__(512) void smax_out2_k(
    const float* __restrict__ scores, const float* __restrict__ enc_out,
    const float* __restrict__ out_W, const float* __restrict__ lsrc,
    const int* __restrict__ lens,
    const float* __restrict__ dec_all, const float* __restrict__ lg_h_all,
    float* __restrict__ dec_sel, float* __restrict__ lg_sel,
    float* __restrict__ negent_acc, float* __restrict__ logp_acc,
    float* __restrict__ out, int t)
{
    __shared__ float sc[S_];
    __shared__ float comb[H_];
    __shared__ float lg[V_];
    __shared__ int tok_s;
    const int tid = threadIdx.x;
    const int b = blockIdx.x;
    const int lane = tid & 63, wv = tid >> 6;
    if (wv == 0) {
        float m = -1e30f;
        for (int s = lane; s < S_; s += 64) {
            float v = scores[b * S_ + s]; sc[s] = v; m = fmaxf(m, v);
        }
        for (int d = 32; d; d >>= 1) m = fmaxf(m, __shfl_xor(m, d));
        float sum = 0.f;
        for (int s = lane; s < S_; s += 64) {
            float e = expf(sc[s] - m); sc[s] = e; sum += e;
        }
        for (int d = 32; d; d >>= 1) sum += __shfl_xor(sum, d);
        float inv = 1.f / sum;
        for (int s = lane; s < S_; s += 64) {
            float pr = sc[s] * inv; sc[s] = pr;
            out[T_ * B_ + ((size_t)b * T_ + t) * S_ + s] = pr;
        }
    }
    __syncthreads();
    {   // context: 2 h per thread (float2), 4-way s-ILP, len-bounded
        const int len4 = (lens[b] + 3) & ~3;
        const float* base = enc_out + (size_t)b * H_ + tid * 2;
        float2 ac0 = {0,0}, ac1 = {0,0}, ac2 = {0,0}, ac3 = {0,0};
        for (int s = 0; s < len4; s += 4) {
            float2 e0 = *(const float2*)(base + (size_t)(s    ) * B_ * H_);
            float2 e1 = *(const float2*)(base + (size_t)(s + 1) * B_ * H_);
            float2 e2 = *(const float2*)(base + (size_t)(s + 2) * B_ * H_);
            float2 e3 = *(const float2*)(base + (size_t)(s + 3) * B_ * H_);
            float p0 = sc[s], p1 = sc[s + 1], p2 = sc[s + 2], p3 = sc[s + 3];
            ac0.x = fmaf(p0, e0.x, ac0.x); ac0.y = fmaf(p0, e0.y, ac0.y);
            ac1.x = fmaf(p1, e1.x, ac1.x); ac1.y = fmaf(p1, e1.y, ac1.y);
            ac2.x = fmaf(p2, e2.x, ac2.x); ac2.y = fmaf(p2, e2.y, ac2.y);
            ac3.x = fmaf(p3, e3.x, ac3.x); ac3.y = fmaf(p3, e3.y, ac3.y);
        }
        comb[tid * 2 + 0] = ac0.x + ac1.x + ac2.x + ac3.x;
        comb[tid * 2 + 1] = ac0.y + ac1.y + ac2.y + ac3.y;
    }
    __syncthreads();
    {   // ctx-half logits: wave wv handles v in [wv*8, wv*8+8)
        for (int v = wv * 8; v < wv * 8 + 8; ++v) {
            const float* w = out_W + (size_t)v * (2 * H_);
            float a0 = 0.f, a1 = 0.f;
#pragma unroll
            for (int j = 0; j < 16; j += 2) {
                a0 = fmaf(comb[lane + j * 64], w[lane + j * 64], a0);
                a1 = fmaf(comb[lane + (j + 1) * 64], w[lane + (j + 1) * 64], a1);
            }
            float acc = a0 + a1;
            for (int d = 32; d; d >>= 1) acc += __shfl_xor(acc, d);
            if (lane == 0) lg[v] = acc + lsrc[(size_t)b * V_ + v];
        }
    }
    __syncthreads();
    if (wv == 0) {
        float x = lg[lane];
        float m = x;
        for (int d = 32; d; d >>= 1) m = fmaxf(m, __shfl_xor(m, d));
        float e = expf(x - m);
        float s = e;
        for (int d = 32; d; d >>= 1) s += __shfl_xor(s, d);
        float pr = e / s;
        float ps = pr;
        for (int d = 32; d; d >>= 1) ps += __shfl_xor(ps, d);
        pr = pr / ps;   // reference renormalizes
        float bv = pr; int bi = lane;
        for (int d = 32; d; d >>= 1) {
            float ov = __shfl_xor(bv, d); int oi = __shfl_xor(bi, d);
            if (ov > bv || (ov == bv && oi < bi)) { bv = ov; bi = oi; }
        }
        float ne = pr * logf(pr + 1e-6f);
        for (int d = 32; d; d >>= 1) ne += __shfl_xor(ne, d);
        float ptok = __shfl(pr, bi);
        if (lane == 0) {
            out[t * B_ + b] = (float)bi;
            float na = negent_acc[b] + ne;                negent_acc[b] = na;
            float la = logp_acc[b] + logf(ptok + 1e-6f);  logp_acc[b] = la;
            if (t == T_ - 1) {
                out[T_ * B_ + B_ * T_ * S_ + b] = na;
                out[T_ * B_ + B_ * T_ * S_ + B_ + b] = la;
            }
            tok_s = bi;
        }
    }
    __syncthreads();
    {   // value-gather next-step inputs (float2 over 512 threads)
        const int tk = tok_s;
        const float2* src = (const float2*)(dec_all + (size_t)(tk * 64 + b) * H_);
        float2* dst = (float2*)(dec_sel + (size_t)b * H_);
        dst[tid] = src[tid];
        if (tid < V_)
            lg_sel[(size_t)b * V_ + tid] = lg_h_all[(size_t)(tk * 64 + b) * V_ + tid];
    }
}

// ------------------- fallback path kernels (validated R15) -----------------
__global__ __launch_bounds__(256) void lstm_gather_k(
    const float* __restrict__ gsrc, size_t strideB,
    const float* __restrict__ hh_gates, const float* __restrict__ enc_c0,
    float* __restrict__ out_h)
{
    int idx = blockIdx.x * 256 + threadIdx.x;
    int b = idx >> 10, h = idx & (H_ - 1);
    const float* ag = gsrc + (size_t)b * strideB;
    const float* hg = hh_gates + (size_t)b * H4_;
    float gi = ag[h]           + hg[h];
    float gf = ag[H_ + h]      + hg[H_ + h];
    float gg = ag[2 * H_ + h]  + hg[2 * H_ + h];
    float go = ag[3 * H_ + h]  + hg[3 * H_ + h];
    float cc = sigm(gf) * enc_c0[idx] + sigm(gi) * tanhf(gg);
    out_h[idx] = sigm(go) * tanhf(cc);
}

__global__ __launch_bounds__(256) void score_k(
    const float* __restrict__ enc_t, const float* __restrict__ dec_part,
    const float* __restrict__ dec_b, const float* __restrict__ attn_W,
    const float* __restrict__ attn_b, const int* __restrict__ lens,
    float* __restrict__ scores)
{
    const int lane = threadIdx.x & 63;
    const int gw = blockIdx.x * 4 + (threadIdx.x >> 6);
    const int b = gw >> 5, sg = gw & 31;
    float dec_r[16], aw_r[16];
#pragma unroll
    for (int it = 0; it < 16; ++it) {
        int h = lane + it * 64;
        dec_r[it] = dec_part[(size_t)b * H_ + h]
                  + dec_part[(size_t)(B_ + b) * H_ + h]
                  + dec_part[(size_t)(2 * B_ + b) * H_ + h]
                  + dec_part[(size_t)(3 * B_ + b) * H_ + h]
                  + dec_b[h];
        aw_r[it] = attn_W[h];
    }
    const int len = lens[b];
    const float ab = attn_b[0];
    for (int s = sg * 5; s < sg * 5 + 5; ++s) {
        if (s >= len) { if (lane == 0) scores[b * S_ + s] = -1e9f; continue; }
        const float* ep = enc_t + ((size_t)s * B_ + b) * H_;
        float acc = 0.f;
#pragma unroll
        for (int it = 0; it < 16; ++it)
            acc += aw_r[it] * tanhf(ep[lane + it * 64] + dec_r[it]);
        for (int d = 32; d; d >>= 1) acc += __shfl_xor(acc, d);
        if (lane == 0) scores[b * S_ + s] = acc + ab;
    }
}

__global__ __launch_bounds__(256) void smax_out_k(
    const float* __restrict__ scores, const float* __restrict__ enc_out,
    const float* __restrict__ out_h, const float* __restrict__ out_W,
    const float* __restrict__ out_b, const float* __restrict__ all_gates,
    const int* __restrict__ lens, float* __restrict__ gates_sel,
    float* __restrict__ negent_acc, float* __restrict__ logp_acc,
    float* __restrict__ out, int t)
{
    __shared__ float sc[S_];
    __shared__ float comb[2 * H_];
    __shared__ float lg[V_];
    __shared__ int tok_s;
    const int tid = threadIdx.x;
    const int b = blockIdx.x;
    const int lane = tid & 63, wv = tid >> 6;
    if (wv == 0) {
        float m = -1e30f;
        for (int s = lane; s < S_; s += 64) {
            float v = scores[b * S_ + s]; sc[s] = v; m = fmaxf(m, v);
        }
        for (int d = 32; d; d >>= 1) m = fmaxf(m, __shfl_xor(m, d));
        float sum = 0.f;
        for (int s = lane; s < S_; s += 64) {
            float e = expf(sc[s] - m); sc[s] = e; sum += e;
        }
        for (int d = 32; d; d >>= 1) sum += __shfl_xor(sum, d);
        float inv = 1.f / sum;
        for (int s = lane; s < S_; s += 64) {
            float pr = sc[s] * inv; sc[s] = pr;
            out[T_ * B_ + ((size_t)b * T_ + t) * S_ + s] = pr;
        }
    }
    __syncthreads();
    {
        const int len4 = (lens[b] + 3) & ~3;
        const float* base = enc_out + (size_t)b * H_ + tid * 4;
        float4 ac0 = {0,0,0,0}, ac1 = {0,0,0,0}, ac2 = {0,0,0,0}, ac3 = {0,0,0,0};
        for (int s = 0; s < len4; s += 4) {
            float4 e0 = *(const float4*)(base + (size_t)(s    ) * B_ * H_);
            float4 e1 = *(const float4*)(base + (size_t)(s + 1) * B_ * H_);
            float4 e2 = *(const float4*)(base + (size_t)(s + 2) * B_ * H_);
            float4 e3 = *(const float4*)(base + (size_t)(s + 3) * B_ * H_);
            float p0 = sc[s], p1 = sc[s + 1], p2 = sc[s + 2], p3 = sc[s + 3];
            ac0.x = fmaf(p0, e0.x, ac0.x); ac0.y = fmaf(p0, e0.y, ac0.y);
            ac0.z = fmaf(p0, e0.z, ac0.z); ac0.w = fmaf(p0, e0.w, ac0.w);
            ac1.x = fmaf(p1, e1.x, ac1.x); ac1.y = fmaf(p1, e1.y, ac1.y);
            ac1.z = fmaf(p1, e1.z, ac1.z); ac1.w = fmaf(p1, e1.w, ac1.w);
            ac2.x = fmaf(p2, e2.x, ac2.x); ac2.y = fmaf(p2, e2.y, ac2.y);
            ac2.z = fmaf(p2, e2.z, ac2.z); ac2.w = fmaf(p2, e2.w, ac2.w);
            ac3.x = fmaf(p3, e3.x, ac3.x); ac3.y = fmaf(p3, e3.y, ac3.y);
            ac3.z = fmaf(p3, e3.z, ac3.z); ac3.w = fmaf(p3, e3.w, ac3.w);
        }
        comb[tid * 4 + 0] = ac0.x + ac1.x + ac2.x + ac3.x;
        comb[tid * 4 + 1] = ac0.y + ac1.y + ac2.y + ac3.y;
        comb[tid * 4 + 2] = ac0.z + ac1.z + ac2.z + ac3.z;
        comb[tid * 4 + 3] = ac0.w + ac1.w + ac2.w + ac3.w;
    }
    for (int i = tid; i < H_; i += 256) comb[H_ + i] = out_h[(size_t)b * H_ + i];
    __syncthreads();
    for (int v = wv * 16; v < wv * 16 + 16; ++v) {
        const float* w = out_W + (size_t)v * (2 * H_);
        float a0 = 0.f, a1 = 0.f;
#pragma unroll
        for (int j = 0; j < 32; j += 2) {
            a0 = fmaf(comb[lane + j * 64], w[lane + j * 64], a0);
            a1 = fmaf(comb[lane + (j + 1) * 64], w[lane + (j + 1) * 64], a1);
        }
        float acc = a0 + a1;
        for (int d = 32; d; d >>= 1) acc += __shfl_xor(acc, d);
        if (lane == 0) lg[v] = acc + out_b[v];
    }
    __syncthreads();
    if (wv == 0) {
        float x = lg[lane];
        float m = x;
        for (int d = 32; d; d >>= 1) m = fmaxf(m, __shfl_xor(m, d));
        float e = expf(x - m);
        float s = e;
        for (int d = 32; d; d >>= 1) s += __shfl_xor(s, d);
        float pr = e / s;
        float ps = pr;
        for (int d = 32; d; d >>= 1) ps += __shfl_xor(ps, d);
        pr = pr / ps;
        float bv = pr; int bi = lane;
        for (int d = 32; d; d >>= 1) {
            float ov = __shfl_xor(bv, d); int oi = __shfl_xor(bi, d);
            if (ov > bv || (ov == bv && oi < bi)) { bv = ov; bi = oi; }
        }
        float ne = pr * logf(pr + 1e-6f);
        for (int d = 32; d; d >>= 1) ne += __shfl_xor(ne, d);
        float ptok = __shfl(pr, bi);
        if (lane == 0) {
            out[t * B_ + b] = (float)bi;
            float na = negent_acc[b] + ne;                negent_acc[b] = na;
            float la = logp_acc[b] + logf(ptok + 1e-6f);  logp_acc[b] = la;
            if (t == T_ - 1) {
                out[T_ * B_ + B_ * T_ * S_ + b] = na;
                out[T_ * B_ + B_ * T_ * S_ + B_ + b] = la;
            }
            tok_s = bi;
        }
    }
    __syncthreads();
    {
        const int tk = tok_s;
        const float4* src = (const float4*)(all_gates + (size_t)tk * H4_);
        float4* dst = (float4*)(gates_sel + (size_t)b * H4_);
        for (int i = tid; i < H4_ / 4; i += 256) dst[i] = src[i];
    }
}

extern "C" void kernel_launch(void* const* d_in, const int* in_sizes, int n_in,
                              void* d_out, int out_size, void* d_ws, size_t ws_size,
                              hipStream_t stream) {
    const float* enc_h0  = (const float*)d_in[0];
    const float* enc_c0  = (const float*)d_in[1];
    const float* enc_out = (const float*)d_in[2];
    const int*   lens    = (const int*)d_in[3];
    const float* tok_emb = (const float*)d_in[4];
    const float* embed   = (const float*)d_in[5];
    const float* W_ih    = (const float*)d_in[6];
    const float* W_hh    = (const float*)d_in[7];
    const float* b_ih    = (const float*)d_in[8];
    const float* b_hh    = (const float*)d_in[9];
    const float* out_W   = (const float*)d_in[10];
    const float* out_b   = (const float*)d_in[11];
    const float* enc_W   = (const float*)d_in[12];
    const float* enc_b   = (const float*)d_in[13];
    const float* dec_W   = (const float*)d_in[14];
    const float* dec_b   = (const float*)d_in[15];
    const float* attn_W  = (const float*)d_in[16];
    const float* attn_b  = (const float*)d_in[17];
    float* out = (float*)d_out;

    float* ws = (float*)d_ws;

    if (ws_size >= 64012800u) {
        // -------- fast path: dec/lg precompute, 2 launches per step --------
        float* hh_gates  = ws;                          // 262144 (unused fast path slot)
        float* dec_sel   = hh_gates + B_ * H4_;         // 65536
        float* lg_sel    = dec_sel + B_ * H_;           // 4096
        float* negent    = lg_sel + B_ * V_;            // 64
        float* logp      = negent + B_;                 // 64
        float* emb_ext   = logp + B_;                   // 65536
        float* all_gates = emb_ext + 128 * E_;          // 524288
        float* lg_h_all  = all_gates + (size_t)128 * H4_;   // 270336
        float* dec_all   = lg_h_all + (size_t)66 * 64 * V_; // 4325376
        float* enc_t     = dec_all + (size_t)66 * 64 * H_;  // 10485760
        // enc_t region aliases (lifetimes disjoint, all dead before enc_t GEMM):
        float* outh_tmp  = enc_t;                 // [0 .. 4,325,376)
        float* part      = enc_t + 4325376;       // [4,325,376 .. 5,373,952) hh partials
        float* dec_p1    = enc_t + 4325376;       // same region, after part dies
        float* scores    = emb_ext;               // dead after all_gates GEMM

        init_k<<<(128 * E_ + 255) / 256, 256, 0, stream>>>(embed, tok_emb, emb_ext,
                                                           negent, logp);
        // hh split-K partials (reduced inline by outh_all_k)
        gemm_part<<<dim3(H4_ / 64, 1, 4), 256, 0, stream>>>(enc_h0, W_hh, part, B_, H4_, H_);
        gemm_part<<<dim3(H4_ / 64, 2, 1), 256, 0, stream>>>(emb_ext, W_ih, all_gates,
                                                            128, H4_, E_);
        outh_all_k<<<(66 * 64 * H_) / 256, 256, 0, stream>>>(all_gates, part, b_ih, b_hh,
                                                             enc_c0, outh_tmp);
        // dec_all = outh_tmp @ dec_W^T + dec_b, split-K=2 (528 blocks)
        gemm_bt_128p<<<dim3(H_ / 128, (66 * 64) / 128, 2), 512, 0, stream>>>(
            outh_tmp, dec_W, dec_all, dec_p1, 66 * 64, H_, H_);
        reduce2_k<<<(66 * 64 * H_ + 255) / 256, 256, 0, stream>>>(
            dec_all, dec_p1, dec_b, dec_all, 66 * 64 * H_, H_);
        lgh_k<<<66, 256, 0, stream>>>(outh_tmp, out_W, out_b, lg_h_all);
        gemm_bt_128<<<dim3(H_ / 128, (S_ * B_) / 128), 512, 0, stream>>>(
            enc_out, enc_W, enc_b, enc_t, S_ * B_, H_, H_);

        for (int t = 0; t < T_; ++t) {
            const float* dsrc = (t == 0) ? (dec_all + (size_t)(64 * 64) * H_) : dec_sel;
            const float* lsrc = (t == 0) ? (lg_h_all + (size_t)(64 * 64) * V_) : lg_sel;
            score_k2<<<512, 256, 0, stream>>>(enc_t, dsrc, attn_W, attn_b, lens, scores);
            smax_out2_k<<<B_, 512, 0, stream>>>(scores, enc_out, out_W, lsrc, lens,
                                                dec_all, lg_h_all, dec_sel, lg_sel,
                                                negent, logp, out, t);
        }
        return;
    }

    // ---------------- fallback path: validated round 15 ---------------------
    float* hh_gates  = ws;                         // 262144
    float* out_h     = hh_gates + B_ * H4_;        // 65536
    float* dec_part  = out_h + B_ * H_;            // 262144
    float* scores    = dec_part + 4 * B_ * H_;     // 10240
    float* negent    = scores + B_ * S_;           // 64
    float* logp      = negent + B_;                // 64
    float* gates_sel = logp + B_;                  // 262144
    float* emb_ext   = gates_sel + B_ * H4_;       // 65536
    float* all_gates = emb_ext + 128 * E_;         // 524288
    float* enc_t     = all_gates + (size_t)128 * H4_;  // 10485760
    float* part      = enc_t;
    if (ws_size < 47751680u) return;

    init_k<<<(128 * E_ + 255) / 256, 256, 0, stream>>>(embed, tok_emb, emb_ext,
                                                       negent, logp);
    gemm_part<<<dim3(H4_ / 64, 1, 4), 256, 0, stream>>>(enc_h0, W_hh, part, B_, H4_, H_);
    reduce_partials<<<(B_ * H4_ + 255) / 256, 256, 0, stream>>>(
        part, 4, b_ih, b_hh, hh_gates, B_ * H4_, H4_);
    gemm_part<<<dim3(H4_ / 64, 2, 1), 256, 0, stream>>>(emb_ext, W_ih, all_gates,
                                                        128, H4_, E_);
    gemm_bt_128<<<dim3(H_ / 128, (S_ * B_) / 128), 512, 0, stream>>>(
        enc_out, enc_W, enc_b, enc_t, S_ * B_, H_, H_);

    for (int t = 0; t < T_; ++t) {
        const float* gsrc = (t == 0) ? (all_gates + (size_t)64 * H4_) : gates_sel;
        const size_t strideB = (t == 0) ? 0 : (size_t)H4_;
        lstm_gather_k<<<(B_ * H_) / 256, 256, 0, stream>>>(gsrc, strideB, hh_gates,
                                                           enc_c0, out_h);
        gemm_part<<<dim3(H_ / 64, 1, 4), 256, 0, stream>>>(out_h, dec_W, dec_part, B_, H_, H_);
        score_k<<<512, 256, 0, stream>>>(enc_t, dec_part, dec_b, attn_W, attn_b, lens, scores);
        smax_out_k<<<64, 256, 0, stream>>>(scores, enc_out, out_h, out_W, out_b,
                                           all_gates, lens, gates_sel, negent, logp, out, t);
    }
}

// Round 20
// 1447.454 us; speedup vs baseline: 2.0258x; 1.0046x over previous
//
#include <hip/hip_runtime.h>

#define S_ 160
#define B_ 64
#define H_ 1024
#define E_ 512
#define V_ 64
#define T_ 16
#define H4_ 4096

__device__ __forceinline__ float sigm(float x) { return 1.f / (1.f + expf(-x)); }

// ---------------------------------------------------------------------------
// C = A @ Bm^T + bias. 128x128 tile, BK=16, 512 threads, 4x8 acc/thread.
// (validated rounds 15-19)
// ---------------------------------------------------------------------------
__global__ __launch_bounds__(512) void gemm_bt_128(
    const float* __restrict__ A, const float* __restrict__ Bm,
    const float* __restrict__ bias, float* __restrict__ Cd,
    int M, int N, int K)
{
    __shared__ float As[16][132];
    __shared__ float Bs[16][132];
    const int bn = blockIdx.x, bm = blockIdx.y;
    const int tid = threadIdx.x;
    const int lr = tid >> 2, lk = (tid & 3) * 4;
    const int cx4 = (tid & 15) * 4, ry4 = (tid >> 4) * 4;
    const float* Ap = A + (size_t)(bm * 128 + lr) * K + lk;
    const float* Bp = Bm + (size_t)(bn * 128 + lr) * K + lk;
    float acc[4][8] = {};
    for (int k0 = 0; k0 < K; k0 += 16) {
        float4 av = *(const float4*)(Ap + k0);
        float4 bv = *(const float4*)(Bp + k0);
        __syncthreads();
        As[lk + 0][lr] = av.x; As[lk + 1][lr] = av.y;
        As[lk + 2][lr] = av.z; As[lk + 3][lr] = av.w;
        Bs[lk + 0][lr] = bv.x; Bs[lk + 1][lr] = bv.y;
        Bs[lk + 2][lr] = bv.z; Bs[lk + 3][lr] = bv.w;
        __syncthreads();
#pragma unroll
        for (int kk = 0; kk < 16; ++kk) {
            float a[4], b[8];
            *(float4*)(a)     = *(const float4*)&As[kk][ry4];
            *(float4*)(b)     = *(const float4*)&Bs[kk][cx4];
            *(float4*)(b + 4) = *(const float4*)&Bs[kk][64 + cx4];
#pragma unroll
            for (int i = 0; i < 4; ++i)
#pragma unroll
                for (int j = 0; j < 8; ++j) acc[i][j] = fmaf(a[i], b[j], acc[i][j]);
        }
    }
#pragma unroll
    for (int i = 0; i < 4; ++i) {
        int row = bm * 128 + ry4 + i;
#pragma unroll
        for (int j = 0; j < 8; ++j) {
            int col = bn * 128 + ((j < 4) ? (cx4 + j) : (64 + cx4 + j - 4));
            Cd[(size_t)row * N + col] = acc[i][j] + bias[col];
        }
    }
}

// Same tile, split-K=2 partial variant: kz=0 -> P0, kz=1 -> P1 (no bias).
__global__ __launch_bounds__(512) void gemm_bt_128p(
    const float* __restrict__ A, const float* __restrict__ Bm,
    float* __restrict__ P0, float* __restrict__ P1,
    int M, int N, int K)
{
    __shared__ float As[16][132];
    __shared__ float Bs[16][132];
    const int bn = blockIdx.x, bm = blockIdx.y, kz = blockIdx.z;
    const int tid = threadIdx.x;
    const int lr = tid >> 2, lk = (tid & 3) * 4;
    const int cx4 = (tid & 15) * 4, ry4 = (tid >> 4) * 4;
    const int kLen = K / 2, k0b = kz * kLen;
    const float* Ap = A + (size_t)(bm * 128 + lr) * K + k0b + lk;
    const float* Bp = Bm + (size_t)(bn * 128 + lr) * K + k0b + lk;
    float acc[4][8] = {};
    for (int k0 = 0; k0 < kLen; k0 += 16) {
        float4 av = *(const float4*)(Ap + k0);
        float4 bv = *(const float4*)(Bp + k0);
        __syncthreads();
        As[lk + 0][lr] = av.x; As[lk + 1][lr] = av.y;
        As[lk + 2][lr] = av.z; As[lk + 3][lr] = av.w;
        Bs[lk + 0][lr] = bv.x; Bs[lk + 1][lr] = bv.y;
        Bs[lk + 2][lr] = bv.z; Bs[lk + 3][lr] = bv.w;
        __syncthreads();
#pragma unroll
        for (int kk = 0; kk < 16; ++kk) {
            float a[4], b[8];
            *(float4*)(a)     = *(const float4*)&As[kk][ry4];
            *(float4*)(b)     = *(const float4*)&Bs[kk][cx4];
            *(float4*)(b + 4) = *(const float4*)&Bs[kk][64 + cx4];
#pragma unroll
            for (int i = 0; i < 4; ++i)
#pragma unroll
                for (int j = 0; j < 8; ++j) acc[i][j] = fmaf(a[i], b[j], acc[i][j]);
        }
    }
    float* Cp = kz ? P1 : P0;
#pragma unroll
    for (int i = 0; i < 4; ++i) {
        int row = bm * 128 + ry4 + i;
#pragma unroll
        for (int j = 0; j < 8; ++j) {
            int col = bn * 128 + ((j < 4) ? (cx4 + j) : (64 + cx4 + j - 4));
            Cp[(size_t)row * N + col] = acc[i][j];
        }
    }
}

// C[idx] = P0[idx] + P1[idx] + bias[idx % N]   (tier B only)
__global__ void reduce2_k(const float* __restrict__ P0, const float* __restrict__ P1,
                          const float* __restrict__ bias, float* __restrict__ C,
                          int MN, int N)
{
    int idx = blockIdx.x * 256 + threadIdx.x;
    if (idx >= MN) return;
    C[idx] = P0[idx] + P1[idx] + bias[idx % N];
}

// 64x64 tile GEMM helper (BK=16).
__device__ __forceinline__ void tile64(const float* __restrict__ Arow,
                                       const float* __restrict__ Brow,
                                       int K, float acc[4][4],
                                       float* __restrict__ As,
                                       float* __restrict__ Bs)
{
    const int tid = threadIdx.x;
    const int lr = tid >> 2, lc = (tid & 3) << 2;
    const int tx = tid & 15, ty = tid >> 4;
    for (int k0 = 0; k0 < K; k0 += 16) {
        float4 av = *(const float4*)(Arow + k0);
        float4 bv = *(const float4*)(Brow + k0);
        __syncthreads();
        As[lr * 17 + lc + 0] = av.x; As[lr * 17 + lc + 1] = av.y;
        As[lr * 17 + lc + 2] = av.z; As[lr * 17 + lc + 3] = av.w;
        Bs[lr * 17 + lc + 0] = bv.x; Bs[lr * 17 + lc + 1] = bv.y;
        Bs[lr * 17 + lc + 2] = bv.z; Bs[lr * 17 + lc + 3] = bv.w;
        __syncthreads();
#pragma unroll
        for (int kk = 0; kk < 16; ++kk) {
            float a[4], b[4];
#pragma unroll
            for (int i = 0; i < 4; ++i) a[i] = As[(ty * 4 + i) * 17 + kk];
#pragma unroll
            for (int j = 0; j < 4; ++j) b[j] = Bs[(tx * 4 + j) * 17 + kk];
#pragma unroll
            for (int i = 0; i < 4; ++i)
#pragma unroll
                for (int j = 0; j < 4; ++j) acc[i][j] = fmaf(a[i], b[j], acc[i][j]);
        }
    }
    __syncthreads();
}

// Split-K partials: Cpart[kz][M][N]. KS==1 -> plain GEMM to Cpart.
__global__ __launch_bounds__(256) void gemm_part(
    const float* __restrict__ A, const float* __restrict__ Bm,
    float* __restrict__ Cpart, int M, int N, int K)
{
    __shared__ float smem[2176];
    const int bn = blockIdx.x, bm = blockIdx.y, kz = blockIdx.z, KS = gridDim.z;
    const int tid = threadIdx.x;
    const int lr = tid >> 2, lc = (tid & 3) << 2;
    const int tx = tid & 15, ty = tid >> 4;
    const int kLen = K / KS, k0base = kz * kLen;
    float acc[4][4] = {};
    tile64(A + (size_t)(bm * 64 + lr) * K + k0base + lc,
           Bm + (size_t)(bn * 64 + lr) * K + k0base + lc,
           kLen, acc, smem, smem + 1088);
    float* Cp = Cpart + (size_t)kz * M * N;
#pragma unroll
    for (int i = 0; i < 4; ++i) {
        int row = bm * 64 + ty * 4 + i;
#pragma unroll
        for (int j = 0; j < 4; ++j)
            Cp[(size_t)row * N + bn * 64 + tx * 4 + j] = acc[i][j];
    }
}

__global__ void reduce_partials(const float* __restrict__ Cpart, int KS,
                                const float* __restrict__ bias,
                                const float* __restrict__ bias2,
                                float* __restrict__ C, int MN, int N)
{
    int idx = blockIdx.x * 256 + threadIdx.x;
    if (idx >= MN) return;
    float v = 0.f;
    for (int z = 0; z < KS; ++z) v += Cpart[(size_t)z * MN + idx];
    int col = idx % N;
    if (bias)  v += bias[col];
    if (bias2) v += bias2[col];
    C[idx] = v;
}

// emb_ext rows 0..63 = embed, 64 = tok_emb(SOS), 65..127 = 0; zero accums.
__global__ void init_k(const float* __restrict__ embed, const float* __restrict__ tok_emb,
                       float* __restrict__ emb_ext,
                       float* __restrict__ negent, float* __restrict__ logp)
{
    int i = blockIdx.x * 256 + threadIdx.x;
    if (i < 128 * E_) {
        int r = i >> 9, c = i & (E_ - 1);
        emb_ext[i] = (r < 64) ? embed[r * E_ + c] : ((r == 64) ? tok_emb[c] : 0.f);
    }
    if (i < B_) { negent[i] = 0.f; logp[i] = 0.f; }
}

// ---------------------------------------------------------------------------
// Merged setup: blocks 0-255 = hh split-K partials (bn=blk&63, kz=blk>>6);
// blocks 256-511 = init (emb_ext fill + accumulator zero). Uniform per-block
// branch; both sides independent.
// ---------------------------------------------------------------------------
__global__ __launch_bounds__(256) void setup1_k(
    const float* __restrict__ enc_h0, const float* __restrict__ W_hh,
    float* __restrict__ part,
    const float* __restrict__ embed, const float* __restrict__ tok_emb,
    float* __restrict__ emb_ext,
    float* __restrict__ negent, float* __restrict__ logp)
{
    __shared__ float smem[2176];
    const int blk = blockIdx.x;
    const int tid = threadIdx.x;
    if (blk < 256) {
        const int bn = blk & 63, kz = blk >> 6;
        const int lr = tid >> 2, lc = (tid & 3) << 2;
        const int tx = tid & 15, ty = tid >> 4;
        float acc[4][4] = {};
        tile64(enc_h0 + (size_t)lr * H_ + kz * 256 + lc,
               W_hh + (size_t)(bn * 64 + lr) * H_ + kz * 256 + lc,
               256, acc, smem, smem + 1088);
        float* Cp = part + (size_t)kz * B_ * H4_;
#pragma unroll
        for (int i = 0; i < 4; ++i)
#pragma unroll
            for (int j = 0; j < 4; ++j)
                Cp[(size_t)(ty * 4 + i) * H4_ + bn * 64 + tx * 4 + j] = acc[i][j];
    } else {
        int i = (blk - 256) * 256 + tid;   // [0, 65536)
        int r = i >> 9, c = i & (E_ - 1);
        emb_ext[i] = (r < 64) ? embed[r * E_ + c] : ((r == 64) ? tok_emb[c] : 0.f);
        if (i < B_) { negent[i] = 0.f; logp[i] = 0.f; }
    }
}

// ---------------------------------------------------------------------------
// out_h_all[(v*64+b)][h] = LSTM(all_gates[v] + sum4(hh_part) + b_ih + b_hh).
// (validated R19)
// ---------------------------------------------------------------------------
__global__ __launch_bounds__(256) void outh_all_k(
    const float* __restrict__ all_gates, const float* __restrict__ hh_part,
    const float* __restrict__ b_ih, const float* __restrict__ b_hh,
    const float* __restrict__ enc_c0, float* __restrict__ outh)
{
    size_t idx = (size_t)blockIdx.x * 256 + threadIdx.x;
    int row = (int)(idx >> 10), h = (int)(idx & (H_ - 1));
    int v = row >> 6, b = row & 63;
    const float* ag = all_gates + (size_t)v * H4_;
    const size_t hb = (size_t)b * H4_;
    const size_t P = (size_t)B_ * H4_;
    float g4[4];
#pragma unroll
    for (int g = 0; g < 4; ++g) {
        size_t c = hb + g * H_ + h;
        g4[g] = ag[g * H_ + h]
              + hh_part[c] + hh_part[P + c] + hh_part[2 * P + c] + hh_part[3 * P + c]
              + b_ih[g * H_ + h] + b_hh[g * H_ + h];
    }
    float cc = sigm(g4[1]) * enc_c0[(size_t)b * H_ + h] + sigm(g4[0]) * tanhf(g4[2]);
    outh[idx] = sigm(g4[3]) * tanhf(cc);
}

// lg_h_all[row][v] = out_h_all[row] . out_W[v][H:2H] + out_b[v].  66 blocks.
__global__ __launch_bounds__(256) void lgh_k(
    const float* __restrict__ outh, const float* __restrict__ out_W,
    const float* __restrict__ out_b, float* __restrict__ lgh)
{
    __shared__ float smem[2176];
    const int bm = blockIdx.x;
    const int tid = threadIdx.x;
    const int lr = tid >> 2, lc = (tid & 3) << 2;
    const int tx = tid & 15, ty = tid >> 4;
    float acc[4][4] = {};
    tile64(outh + (size_t)(bm * 64 + lr) * H_ + lc,
           out_W + (size_t)lr * (2 * H_) + H_ + lc,
           H_, acc, smem, smem + 1088);
#pragma unroll
    for (int i = 0; i < 4; ++i) {
        int row = bm * 64 + ty * 4 + i;
#pragma unroll
        for (int j = 0; j < 4; ++j) {
            int col = tx * 4 + j;
            lgh[(size_t)row * V_ + col] = acc[i][j] + out_b[col];
        }
    }
}

// ---------------------------------------------------------------------------
// Scores, WIDE: 512 blocks x 4 waves; wave (b, sg) does 5 s.
// d1 nullable: dec_r = d1 ? (d0[h] + d1[h] + db[h]) : d0[h].
// ---------------------------------------------------------------------------
__global__ __launch_bounds__(256) void score_k2(
    const float* __restrict__ enc_t, const float* __restrict__ d0,
    const float* __restrict__ d1, const float* __restrict__ db,
    const float* __restrict__ attn_W, const float* __restrict__ attn_b,
    const int* __restrict__ lens, float* __restrict__ scores)
{
    const int lane = threadIdx.x & 63;
    const int gw = blockIdx.x * 4 + (threadIdx.x >> 6);
    const int b = gw >> 5, sg = gw & 31;
    float dec_r[16], aw_r[16];
    const float* dr0 = d0 + (size_t)b * H_;
    if (d1) {
        const float* dr1 = d1 + (size_t)b * H_;
#pragma unroll
        for (int it = 0; it < 16; ++it) {
            int h = lane + it * 64;
            dec_r[it] = dr0[h] + dr1[h] + db[h];
            aw_r[it] = attn_W[h];
        }
    } else {
#pragma unroll
        for (int it = 0; it < 16; ++it) {
            int h = lane + it * 64;
            dec_r[it] = dr0[h];
            aw_r[it] = attn_W[h];
        }
    }
    const int len = lens[b];
    const float ab = attn_b[0];
    for (int s = sg * 5; s < sg * 5 + 5; ++s) {
        if (s >= len) { if (lane == 0) scores[b * S_ + s] = -1e9f; continue; }
        const float* ep = enc_t + ((size_t)s * B_ + b) * H_;
        float acc = 0.f;
#pragma unroll
        for (int it = 0; it < 16; ++it)
            acc += aw_r[it] * tanhf(ep[lane + it * 64] + dec_r[it]);
        for (int d = 32; d; d >>= 1) acc += __shfl_xor(acc, d);
        if (lane == 0) scores[b * S_ + s] = acc + ab;
    }
}

// ---------------------------------------------------------------------------
// Tail, 512 threads: softmax + attn-out + context + ctx-half logits +
// renorm/argmax/stats + value-gather. dp1 nullable: gather sums P0+P1+db.
// ---------------------------------------------------------------------------
__global__ __launch_bounds__(512) void smax_out2_k(
    const float* __restrict__ scores, const float* __restrict__ enc_out,
    const float* __restrict__ out_W, const float* __restrict__ lsrc,
    const int* __restrict__ lens,
    const float* __restrict__ decP0, const float* __restrict__ dp1,
    const float* __restrict__ db, const float* __restrict__ lg_h_all,
    float* __restrict__ dec_sel, float* __restrict__ lg_sel,
    float* __restrict__ negent_acc, float* __restrict__ logp_acc,
    float* __restrict__ out, int t)
{
    __shared__ float sc[S_];
    __shared__ float comb[H_];
    __shared__ float lg[V_];
    __shared__ int tok_s;
    const int tid = threadIdx.x;
    const int b = blockIdx.x;
    const int lane = tid & 63, wv = tid >> 6;
    if (wv == 0) {
        float m = -1e30f;
        for (int s = lane; s < S_; s += 64) {
            float v = scores[b * S_ + s]; sc[s] = v; m = fmaxf(m, v);
        }
        for (int d = 32; d; d >>= 1) m = fmaxf(m, __shfl_xor(m, d));
        float sum = 0.f;
        for (int s = lane; s < S_; s += 64) {
            float e = expf(sc[s] - m); sc[s] = e; sum += e;
        }
        for (int d = 32; d; d >>= 1) sum += __shfl_xor(sum, d);
        float inv = 1.f / sum;
        for (int s = lane; s < S_; s += 64) {
            float pr = sc[s] * inv; sc[s] = pr;
            out[T_ * B_ + ((size_t)b * T_ + t) * S_ + s] = pr;
        }
    }
    __syncthreads();
    {   // context: 2 h per thread (float2), 4-way s-ILP, len-bounded
        const int len4 = (lens[b] + 3) & ~3;
        const float* base = enc_out + (size_t)b * H_ + tid * 2;
        float2 ac0 = {0,0}, ac1 = {0,0}, ac2 = {0,0}, ac3 = {0,0};
        for (int s = 0; s < len4; s += 4) {
            float2 e0 = *(const float2*)(base + (size_t)(s    ) * B_ * H_);
            float2 e1 = *(const float2*)(base + (size_t)(s + 1) * B_ * H_);
            float2 e2 = *(const float2*)(base + (size_t)(s + 2) * B_ * H_);
            float2 e3 = *(const float2*)(base + (size_t)(s + 3) * B_ * H_);
            float p0 = sc[s], p1 = sc[s + 1], p2 = sc[s + 2], p3 = sc[s + 3];
            ac0.x = fmaf(p0, e0.x, ac0.x); ac0.y = fmaf(p0, e0.y, ac0.y);
            ac1.x = fmaf(p1, e1.x, ac1.x); ac1.y = fmaf(p1, e1.y, ac1.y);
            ac2.x = fmaf(p2, e2.x, ac2.x); ac2.y = fmaf(p2, e2.y, ac2.y);
            ac3.x = fmaf(p3, e3.x, ac3.x); ac3.y = fmaf(p3, e3.y, ac3.y);
        }
        comb[tid * 2 + 0] = ac0.x + ac1.x + ac2.x + ac3.x;
        comb[tid * 2 + 1] = ac0.y + ac1.y + ac2.y + ac3.y;
    }
    __syncthreads();
    {   // ctx-half logits: wave wv handles v in [wv*8, wv*8+8)
        for (int v = wv * 8; v < wv * 8 + 8; ++v) {
            const float* w = out_W + (size_t)v * (2 * H_);
            float a0 = 0.f, a1 = 0.f;
#pragma unroll
            for (int j = 0; j < 16; j += 2) {
                a0 = fmaf(comb[lane + j * 64], w[lane + j * 64], a0);
                a1 = fmaf(comb[lane + (j + 1) * 64], w[lane + (j + 1) * 64], a1);
            }
            float acc = a0 + a1;
            for (int d = 32; d; d >>= 1) acc += __shfl_xor(acc, d);
            if (lane == 0) lg[v] = acc + lsrc[(size_t)b * V_ + v];
        }
    }
    __syncthreads();
    if (wv == 0) {
        float x = lg[lane];
        float m = x;
        for (int d = 32; d; d >>= 1) m = fmaxf(m, __shfl_xor(m, d));
        float e = expf(x - m);
        float s = e;
        for (int d = 32; d; d >>= 1) s += __shfl_xor(s, d);
        float pr = e / s;
        float ps = pr;
        for (int d = 32; d; d >>= 1) ps += __shfl_xor(ps, d);
        pr = pr / ps;   // reference renormalizes
        float bv = pr; int bi = lane;
        for (int d = 32; d; d >>= 1) {
            float ov = __shfl_xor(bv, d); int oi = __shfl_xor(bi, d);
            if (ov > bv || (ov == bv && oi < bi)) { bv = ov; bi = oi; }
        }
        float ne = pr * logf(pr + 1e-6f);
        for (int d = 32; d; d >>= 1) ne += __shfl_xor(ne, d);
        float ptok = __shfl(pr, bi);
        if (lane == 0) {
            out[t * B_ + b] = (float)bi;
            float na = negent_acc[b] + ne;                negent_acc[b] = na;
            float la = logp_acc[b] + logf(ptok + 1e-6f);  logp_acc[b] = la;
            if (t == T_ - 1) {
                out[T_ * B_ + B_ * T_ * S_ + b] = na;
                out[T_ * B_ + B_ * T_ * S_ + B_ + b] = la;
            }
            tok_s = bi;
        }
    }
    __syncthreads();
    {   // value-gather next-step inputs (float2 over 512 threads)
        const int tk = tok_s;
        const float2* s0 = (const float2*)(decP0 + (size_t)(tk * 64 + b) * H_);
        float2* dst = (float2*)(dec_sel + (size_t)b * H_);
        if (dp1) {
            const float2* s1 = (const float2*)(dp1 + (size_t)(tk * 64 + b) * H_);
            float2 a = s0[tid], c = s1[tid];
            float2 bb = *(const float2*)(db + tid * 2);
            dst[tid] = make_float2(a.x + c.x + bb.x, a.y + c.y + bb.y);
        } else {
            dst[tid] = s0[tid];
        }
        if (tid < V_)
            lg_sel[(size_t)b * V_ + tid] = lg_h_all[(size_t)(tk * 64 + b) * V_ + tid];
    }
}

// ------------------- fallback path kernels (validated R15) -----------------
__global__ __launch_bounds__(256) void lstm_gather_k(
    const float* __restrict__ gsrc, size_t strideB,
    const float* __restrict__ hh_gates, const float* __restrict__ enc_c0,
    float* __restrict__ out_h)
{
    int idx = blockIdx.x * 256 + threadIdx.x;
    int b = idx >> 10, h = idx & (H_ - 1);
    const float* ag = gsrc + (size_t)b * strideB;
    const float* hg = hh_gates + (size_t)b * H4_;
    float gi = ag[h]           + hg[h];
    float gf = ag[H_ + h]      + hg[H_ + h];
    float gg = ag[2 * H_ + h]  + hg[2 * H_ + h];
    float go = ag[3 * H_ + h]  + hg[3 * H_ + h];
    float cc = sigm(gf) * enc_c0[idx] + sigm(gi) * tanhf(gg);
    out_h[idx] = sigm(go) * tanhf(cc);
}

__global__ __launch_bounds__(256) void score_k(
    const float* __restrict__ enc_t, const float* __restrict__ dec_part,
    const float* __restrict__ dec_b, const float* __restrict__ attn_W,
    const float* __restrict__ attn_b, const int* __restrict__ lens,
    float* __restrict__ scores)
{
    const int lane = threadIdx.x & 63;
    const int gw = blockIdx.x * 4 + (threadIdx.x >> 6);
    const int b = gw >> 5, sg = gw & 31;
    float dec_r[16], aw_r[16];
#pragma unroll
    for (int it = 0; it < 16; ++it) {
        int h = lane + it * 64;
        dec_r[it] = dec_part[(size_t)b * H_ + h]
                  + dec_part[(size_t)(B_ + b) * H_ + h]
                  + dec_part[(size_t)(2 * B_ + b) * H_ + h]
                  + dec_part[(size_t)(3 * B_ + b) * H_ + h]
                  + dec_b[h];
        aw_r[it] = attn_W[h];
    }
    const int len = lens[b];
    const float ab = attn_b[0];
    for (int s = sg * 5; s < sg * 5 + 5; ++s) {
        if (s >= len) { if (lane == 0) scores[b * S_ + s] = -1e9f; continue; }
        const float* ep = enc_t + ((size_t)s * B_ + b) * H_;
        float acc = 0.f;
#pragma unroll
        for (int it = 0; it < 16; ++it)
            acc += aw_r[it] * tanhf(ep[lane + it * 64] + dec_r[it]);
        for (int d = 32; d; d >>= 1) acc += __shfl_xor(acc, d);
        if (lane == 0) scores[b * S_ + s] = acc + ab;
    }
}

__global__ __launch_bounds__(256) void smax_out_k(
    const float* __restrict__ scores, const float* __restrict__ enc_out,
    const float* __restrict__ out_h, const float* __restrict__ out_W,
    const float* __restrict__ out_b, const float* __restrict__ all_gates,
    const int* __restrict__ lens, float* __restrict__ gates_sel,
    float* __restrict__ negent_acc, float* __restrict__ logp_acc,
    float* __restrict__ out, int t)
{
    __shared__ float sc[S_];
    __shared__ float comb[2 * H_];
    __shared__ float lg[V_];
    __shared__ int tok_s;
    const int tid = threadIdx.x;
    const int b = blockIdx.x;
    const int lane = tid & 63, wv = tid >> 6;
    if (wv == 0) {
        float m = -1e30f;
        for (int s = lane; s < S_; s += 64) {
            float v = scores[b * S_ + s]; sc[s] = v; m = fmaxf(m, v);
        }
        for (int d = 32; d; d >>= 1) m = fmaxf(m, __shfl_xor(m, d));
        float sum = 0.f;
        for (int s = lane; s < S_; s += 64) {
            float e = expf(sc[s] - m); sc[s] = e; sum += e;
        }
        for (int d = 32; d; d >>= 1) sum += __shfl_xor(sum, d);
        float inv = 1.f / sum;
        for (int s = lane; s < S_; s += 64) {
            float pr = sc[s] * inv; sc[s] = pr;
            out[T_ * B_ + ((size_t)b * T_ + t) * S_ + s] = pr;
        }
    }
    __syncthreads();
    {
        const int len4 = (lens[b] + 3) & ~3;
        const float* base = enc_out + (size_t)b * H_ + tid * 4;
        float4 ac0 = {0,0,0,0}, ac1 = {0,0,0,0}, ac2 = {0,0,0,0}, ac3 = {0,0,0,0};
        for (int s = 0; s < len4; s += 4) {
            float4 e0 = *(const float4*)(base + (size_t)(s    ) * B_ * H_);
            float4 e1 = *(const float4*)(base + (size_t)(s + 1) * B_ * H_);
            float4 e2 = *(const float4*)(base + (size_t)(s + 2) * B_ * H_);
            float4 e3 = *(const float4*)(base + (size_t)(s + 3) * B_ * H_);
            float p0 = sc[s], p1 = sc[s + 1], p2 = sc[s + 2], p3 = sc[s + 3];
            ac0.x = fmaf(p0, e0.x, ac0.x); ac0.y = fmaf(p0, e0.y, ac0.y);
            ac0.z = fmaf(p0, e0.z, ac0.z); ac0.w = fmaf(p0, e0.w, ac0.w);
            ac1.x = fmaf(p1, e1.x, ac1.x); ac1.y = fmaf(p1, e1.y, ac1.y);
            ac1.z = fmaf(p1, e1.z, ac1.z); ac1.w = fmaf(p1, e1.w, ac1.w);
            ac2.x = fmaf(p2, e2.x, ac2.x); ac2.y = fmaf(p2, e2.y, ac2.y);
            ac2.z = fmaf(p2, e2.z, ac2.z); ac2.w = fmaf(p2, e2.w, ac2.w);
            ac3.x = fmaf(p3, e3.x, ac3.x); ac3.y = fmaf(p3, e3.y, ac3.y);
            ac3.z = fmaf(p3, e3.z, ac3.z); ac3.w = fmaf(p3, e3.w, ac3.w);
        }
        comb[tid * 4 + 0] = ac0.x + ac1.x + ac2.x + ac3.x;
        comb[tid * 4 + 1] = ac0.y + ac1.y + ac2.y + ac3.y;
        comb[tid * 4 + 2] = ac0.z + ac1.z + ac2.z + ac3.z;
        comb[tid * 4 + 3] = ac0.w + ac1.w + ac2.w + ac3.w;
    }
    for (int i = tid; i < H_; i += 256) comb[H_ + i] = out_h[(size_t)b * H_ + i];
    __syncthreads();
    for (int v = wv * 16; v < wv * 16 + 16; ++v) {
        const float* w = out_W + (size_t)v * (2 * H_);
        float a0 = 0.f, a1 = 0.f;
#pragma unroll
        for (int j = 0; j < 32; j += 2) {
            a0 = fmaf(comb[lane + j * 64], w[lane + j * 64], a0);
            a1 = fmaf(comb[lane + (j + 1) * 64], w[lane + (j + 1) * 64], a1);
        }
        float acc = a0 + a1;
        for (int d = 32; d; d >>= 1) acc += __shfl_xor(acc, d);
        if (lane == 0) lg[v] = acc + out_b[v];
    }
    __syncthreads();
    if (wv == 0) {
        float x = lg[lane];
        float m = x;
        for (int d = 32; d; d >>= 1) m = fmaxf(m, __shfl_xor(m, d));
        float e = expf(x - m);
        float s = e;
        for (int d = 32; d; d >>= 1) s += __shfl_xor(s, d);
        float pr = e / s;
        float ps = pr;
        for (int d = 32; d; d >>= 1) ps += __shfl_xor(ps, d);
        pr = pr / ps;
        float bv = pr; int bi = lane;
        for (int d = 32; d; d >>= 1) {
            float ov = __shfl_xor(bv, d); int oi = __shfl_xor(bi, d);
            if (ov > bv || (ov == bv && oi < bi)) { bv = ov; bi = oi; }
        }
        float ne = pr * logf(pr + 1e-6f);
        for (int d = 32; d; d >>= 1) ne += __shfl_xor(ne, d);
        float ptok = __shfl(pr, bi);
        if (lane == 0) {
            out[t * B_ + b] = (float)bi;
            float na = negent_acc[b] + ne;                negent_acc[b] = na;
            float la = logp_acc[b] + logf(ptok + 1e-6f);  logp_acc[b] = la;
            if (t == T_ - 1) {
                out[T_ * B_ + B_ * T_ * S_ + b] = na;
                out[T_ * B_ + B_ * T_ * S_ + B_ + b] = la;
            }
            tok_s = bi;
        }
    }
    __syncthreads();
    {
        const int tk = tok_s;
        const float4* src = (const float4*)(all_gates + (size_t)tk * H4_);
        float4* dst = (float4*)(gates_sel + (size_t)b * H4_);
        for (int i = tid; i < H4_ / 4; i += 256) dst[i] = src[i];
    }
}

extern "C" void kernel_launch(void* const* d_in, const int* in_sizes, int n_in,
                              void* d_out, int out_size, void* d_ws, size_t ws_size,
                              hipStream_t stream) {
    const float* enc_h0  = (const float*)d_in[0];
    const float* enc_c0  = (const float*)d_in[1];
    const float* enc_out = (const float*)d_in[2];
    const int*   lens    = (const int*)d_in[3];
    const float* tok_emb = (const float*)d_in[4];
    const float* embed   = (const float*)d_in[5];
    const float* W_ih    = (const float*)d_in[6];
    const float* W_hh    = (const float*)d_in[7];
    const float* b_ih    = (const float*)d_in[8];
    const float* b_hh    = (const float*)d_in[9];
    const float* out_W   = (const float*)d_in[10];
    const float* out_b   = (const float*)d_in[11];
    const float* enc_W   = (const float*)d_in[12];
    const float* enc_b   = (const float*)d_in[13];
    const float* dec_W   = (const float*)d_in[14];
    const float* dec_b   = (const float*)d_in[15];
    const float* attn_W  = (const float*)d_in[16];
    const float* attn_b  = (const float*)d_in[17];
    float* out = (float*)d_out;

    float* ws = (float*)d_ws;

    if (ws_size >= 80265728u) {
        // ------ tier A: dedicated P1, no reduce2, 6 setup launches ---------
        float* dec_sel   = ws;                          // 65536
        float* lg_sel    = dec_sel + B_ * H_;           // 4096
        float* negent    = lg_sel + B_ * V_;            // 64
        float* logp      = negent + B_;                 // 64
        float* emb_ext   = logp + B_;                   // 65536
        float* all_gates = emb_ext + 128 * E_;          // 524288
        float* lg_h_all  = all_gates + (size_t)128 * H4_;   // 270336
        float* dec_P0    = lg_h_all + (size_t)66 * 64 * V_; // 4325376
        float* dec_P1    = dec_P0 + (size_t)66 * 64 * H_;   // 4325376
        float* enc_t     = dec_P1 + (size_t)66 * 64 * H_;   // 10485760
        // enc_t region aliases (dead before enc_t GEMM):
        float* outh_tmp  = enc_t;                 // [0 .. 4,325,376)
        float* part      = enc_t + 4325376;       // [.. +1,048,576) hh partials
        float* scores    = emb_ext;               // dead after all_gates GEMM

        setup1_k<<<512, 256, 0, stream>>>(enc_h0, W_hh, part, embed, tok_emb,
                                          emb_ext, negent, logp);
        gemm_part<<<dim3(H4_ / 64, 2, 1), 256, 0, stream>>>(emb_ext, W_ih, all_gates,
                                                            128, H4_, E_);
        outh_all_k<<<(66 * 64 * H_) / 256, 256, 0, stream>>>(all_gates, part, b_ih, b_hh,
                                                             enc_c0, outh_tmp);
        gemm_bt_128p<<<dim3(H_ / 128, (66 * 64) / 128, 2), 512, 0, stream>>>(
            outh_tmp, dec_W, dec_P0, dec_P1, 66 * 64, H_, H_);
        lgh_k<<<66, 256, 0, stream>>>(outh_tmp, out_W, out_b, lg_h_all);
        gemm_bt_128<<<dim3(H_ / 128, (S_ * B_) / 128), 512, 0, stream>>>(
            enc_out, enc_W, enc_b, enc_t, S_ * B_, H_, H_);

        for (int t = 0; t < T_; ++t) {
            if (t == 0) {
                score_k2<<<512, 256, 0, stream>>>(
                    enc_t, dec_P0 + (size_t)(64 * 64) * H_,
                    dec_P1 + (size_t)(64 * 64) * H_, dec_b,
                    attn_W, attn_b, lens, scores);
                smax_out2_k<<<B_, 512, 0, stream>>>(
                    scores, enc_out, out_W, lg_h_all + (size_t)(64 * 64) * V_, lens,
                    dec_P0, dec_P1, dec_b, lg_h_all, dec_sel, lg_sel,
                    negent, logp, out, t);
            } else {
                score_k2<<<512, 256, 0, stream>>>(enc_t, dec_sel, nullptr, nullptr,
                                                  attn_W, attn_b, lens, scores);
                smax_out2_k<<<B_, 512, 0, stream>>>(
                    scores, enc_out, out_W, lg_sel, lens,
                    dec_P0, dec_P1, dec_b, lg_h_all, dec_sel, lg_sel,
                    negent, logp, out, t);
            }
        }
        return;
    }

    if (ws_size >= 64012800u) {
        // ------ tier B: R19 fast path + setup1 merge ----------------------
        float* hh_gates  = ws;                          // 262144 (unused slot)
        float* dec_sel   = hh_gates + B_ * H4_;         // 65536
        float* lg_sel    = dec_sel + B_ * H_;           // 4096
        float* negent    = lg_sel + B_ * V_;            // 64
        float* logp      = negent + B_;                 // 64
        float* emb_ext   = logp + B_;                   // 65536
        float* all_gates = emb_ext + 128 * E_;          // 524288
        float* lg_h_all  = all_gates + (size_t)128 * H4_;   // 270336
        float* dec_all   = lg_h_all + (size_t)66 * 64 * V_; // 4325376
        float* enc_t     = dec_all + (size_t)66 * 64 * H_;  // 10485760
        float* outh_tmp  = enc_t;
        float* part      = enc_t + 4325376;
        float* dec_p1    = enc_t + 4325376;   // after part dies
        float* scores    = emb_ext;

        setup1_k<<<512, 256, 0, stream>>>(enc_h0, W_hh, part, embed, tok_emb,
                                          emb_ext, negent, logp);
        gemm_part<<<dim3(H4_ / 64, 2, 1), 256, 0, stream>>>(emb_ext, W_ih, all_gates,
                                                            128, H4_, E_);
        outh_all_k<<<(66 * 64 * H_) / 256, 256, 0, stream>>>(all_gates, part, b_ih, b_hh,
                                                             enc_c0, outh_tmp);
        gemm_bt_128p<<<dim3(H_ / 128, (66 * 64) / 128, 2), 512, 0, stream>>>(
            outh_tmp, dec_W, dec_all, dec_p1, 66 * 64, H_, H_);
        reduce2_k<<<(66 * 64 * H_ + 255) / 256, 256, 0, stream>>>(
            dec_all, dec_p1, dec_b, dec_all, 66 * 64 * H_, H_);
        lgh_k<<<66, 256, 0, stream>>>(outh_tmp, out_W, out_b, lg_h_all);
        gemm_bt_128<<<dim3(H_ / 128, (S_ * B_) / 128), 512, 0, stream>>>(
            enc_out, enc_W, enc_b, enc_t, S_ * B_, H_, H_);

        for (int t = 0; t < T_; ++t) {
            const float* dsrc = (t == 0) ? (dec_all + (size_t)(64 * 64) * H_) : dec_sel;
            const float* lsrc = (t == 0) ? (lg_h_all + (size_t)(64 * 64) * V_) : lg_sel;
            score_k2<<<512, 256, 0, stream>>>(enc_t, dsrc, nullptr, nullptr,
                                              attn_W, attn_b, lens, scores);
            smax_out2_k<<<B_, 512, 0, stream>>>(scores, enc_out, out_W, lsrc, lens,
                                                dec_all, nullptr, nullptr, lg_h_all,
                                                dec_sel, lg_sel, negent, logp, out, t);
        }
        return;
    }

    // ---------------- tier C: validated round 15 fallback -------------------
    float* hh_gates  = ws;                         // 262144
    float* out_h     = hh_gates + B_ * H4_;        // 65536
    float* dec_part  = out_h + B_ * H_;            // 262144
    float* scores    = dec_part + 4 * B_ * H_;     // 10240
    float* negent    = scores + B_ * S_;           // 64
    float* logp      = negent + B_;                // 64
    float* gates_sel = logp + B_;                  // 262144
    float* emb_ext   = gates_sel + B_ * H4_;       // 65536
    float* all_gates = emb_ext + 128 * E_;         // 524288
    float* enc_t     = all_gates + (size_t)128 * H4_;  // 10485760
    float* part      = enc_t;
    if (ws_size < 47751680u) return;

    init_k<<<(128 * E_ + 255) / 256, 256, 0, stream>>>(embed, tok_emb, emb_ext,
                                                       negent, logp);
    gemm_part<<<dim3(H4_ / 64, 1, 4), 256, 0, stream>>>(enc_h0, W_hh, part, B_, H4_, H_);
    reduce_partials<<<(B_ * H4_ + 255) / 256, 256, 0, stream>>>(
        part, 4, b_ih, b_hh, hh_gates, B_ * H4_, H4_);
    gemm_part<<<dim3(H4_ / 64, 2, 1), 256, 0, stream>>>(emb_ext, W_ih, all_gates,
                                                        128, H4_, E_);
    gemm_bt_128<<<dim3(H_ / 128, (S_ * B_) / 128), 512, 0, stream>>>(
        enc_out, enc_W, enc_b, enc_t, S_ * B_, H_, H_);

    for (int t = 0; t < T_; ++t) {
        const float* gsrc = (t == 0) ? (all_gates + (size_t)64 * H4_) : gates_sel;
        const size_t strideB = (t == 0) ? 0 : (size_t)H4_;
        lstm_gather_k<<<(B_ * H_) / 256, 256, 0, stream>>>(gsrc, strideB, hh_gates,
                                                           enc_c0, out_h);
        gemm_part<<<dim3(H_ / 64, 1, 4), 256, 0, stream>>>(out_h, dec_W, dec_part, B_, H_, H_);
        score_k<<<512, 256, 0, stream>>>(enc_t, dec_part, dec_b, attn_W, attn_b, lens, scores);
        smax_out_k<<<64, 256, 0, stream>>>(scores, enc_out, out_h, out_W, out_b,
                                           all_gates, lens, gates_sel, negent, logp, out, t);
    }
}